// Round 5
// baseline (1034.398 us; speedup 1.0000x reference)
//
#include <hip/hip_runtime.h>
#include <stdint.h>

typedef unsigned int uint;
typedef unsigned short ushort;
typedef __attribute__((ext_vector_type(8))) short bf16x8;
typedef __attribute__((ext_vector_type(4))) float f32x4;

#define SR_F 16000.0f
#define NSAMP 160000
#define NB 128
#define FRAME 400
#define HOP 160
#define NF 998
#define NHNR_CHUNK 40
#define JCH 125
#define HNR_LAGS 150
#define TJ 25
#define HWIN (32*TJ + 304)   // 1104 elems

// workspace layout (float offsets)
#define OFF_RMS 0
#define OFF_ZCR (OFF_RMS + NB*NF)
#define OFF_AMP (OFF_ZCR + NB*NF)
#define OFF_F0  (OFF_AMP + NB*NF)
#define OFF_VAL (OFF_F0  + NB*NF)
#define OFF_JIT (OFF_VAL + NB*NF)
#define OFF_HNR (OFF_JIT + NB*4)
#define OFF_MAX (OFF_HNR + NB*NHNR_CHUNK*HNR_LAGS)   // NB uints
#define OFF_MSK (OFF_MAX + NB)                       // NB*2500 u64

__device__ __forceinline__ int imax_(int a, int b) { return a > b ? a : b; }

__device__ __forceinline__ uint pack_bf16(float a, float b) {
    uint ua = __builtin_bit_cast(uint, a), ub = __builtin_bit_cast(uint, b);
    ua = (ua + 0x8000u) >> 16; ub = (ub + 0x8000u) >> 16;
    return ua | (ub << 16);
}

__device__ __forceinline__ bf16x8 ld_b_frag(const uint* p) {
    union { uint u[4]; bf16x8 v; } t;
    t.u[0] = p[0]; t.u[1] = p[1]; t.u[2] = p[2]; t.u[3] = p[3];
    return t.v;
}

__device__ __forceinline__ float sgn_(float v) {
    return (float)(v > 0.f) - (float)(v < 0.f);
}

// ---------------------------------------------------------------------------
// K1: per-frame stats + autocorr peak via MFMA.  4 waves/block, 1 frame/wave.
// Per-wave LDS (dwords): A_pad [0,576) padded (d -> d + 4*(d>>4), conflict-
// free b128), xw [576,1088) shift-0 bf16 pairs, xo [1088,1576) shift-1.
// Also fuses global |a| max: per-frame amp atomicMax + tail wave (f_raw==NF).
// ---------------------------------------------------------------------------
__global__ __launch_bounds__(256) void k_frame(const float* __restrict__ audio,
                                               float* __restrict__ ws)
{
    __shared__ __align__(16) uint lds[4][1576];
    const int tid = threadIdx.x;
    const int widx = tid >> 6, lane = tid & 63;
    const int lo = lane & 15, q = lane >> 4;
    const int s = blockIdx.y;
    const int f_raw = blockIdx.x * 4 + widx;
    const float* as = audio + (size_t)s * NSAMP;

    if (f_raw >= NF) {
        if (f_raw == NF) {   // tail wave: samples [159920,160000) not in any frame
            float m = fabsf(as[NSAMP - 80 + lane]);
            if (lane < 16) m = fmaxf(m, fabsf(as[NSAMP - 16 + lane]));
            #pragma unroll
            for (int off = 32; off; off >>= 1) m = fmaxf(m, __shfl_xor(m, off));
            if (lane == 0)
                atomicMax((uint*)ws + OFF_MAX + s, __float_as_uint(m));
        }
        return;
    }

    uint* Ap = lds[widx];
    uint* xw = Ap + 576;
    uint* xo = Ap + 1088;

    // zero whole per-wave region (pads/boundary zeros), then overwrite data
    {
        uint4 z; z.x = 0; z.y = 0; z.z = 0; z.w = 0;
        uint4* p = (uint4*)Ap;
        for (int i = lane; i < 394; i += 64) p[i] = z;
    }

    const float* a = as + (size_t)f_raw * HOP;
    float ss = 0.f, zc = 0.f, amp = 0.f;
    for (int vi = lane; vi < 100; vi += 64) {
        float4 t = ((const float4*)a)[vi];
        float bn = (vi < 99) ? a[4 * vi + 4] : 0.f;
        ss += t.x * t.x + t.y * t.y + t.z * t.z + t.w * t.w;
        amp = fmaxf(amp, fmaxf(fmaxf(fabsf(t.x), fabsf(t.y)),
                               fmaxf(fabsf(t.z), fabsf(t.w))));
        zc += fabsf(sgn_(t.y) - sgn_(t.x)) + fabsf(sgn_(t.z) - sgn_(t.y))
            + fabsf(sgn_(t.w) - sgn_(t.z));
        if (vi < 99) zc += fabsf(sgn_(bn) - sgn_(t.w));
        uint w0 = pack_bf16(t.x, t.y), w1 = pack_bf16(t.z, t.w);
        uint o0 = pack_bf16(t.y, t.z), o1 = pack_bf16(t.w, bn);
        int d = 248 + 2 * vi;
        xw[d] = w0; xw[d + 1] = w1;
        xo[d] = o0; xo[d + 1] = o1;
        int pv = d + 4 * (d >> 4);
        Ap[pv] = w0; Ap[pv + 1] = w1;
    }
    #pragma unroll
    for (int off = 32; off; off >>= 1) {
        ss += __shfl_xor(ss, off);
        zc += __shfl_xor(zc, off);
        amp = fmaxf(amp, __shfl_xor(amp, off));
    }

    // MFMA K-loop (per-wave arrays; same-wave LDS is in-order, no barrier)
    f32x4 acc1 = {0.f, 0.f, 0.f, 0.f};
    f32x4 acc2 = {0.f, 0.f, 0.f, 0.f};
    const int aoff1 = 496 + 8 * q - 16 * lo;              // elems, mult of 8
    const int ap1 = (aoff1 >> 1) + 4 * (aoff1 >> 5);      // padded dword, mult of 4
    const int ap2 = ap1 - 160;                            // (aoff1-256) padded
    const uint* bw = (lo & 1) ? xo : xw;
    const int boff = 248 + 4 * q + (lo >> 1);
    const ushort* Aus = (const ushort*)Ap;

    #pragma unroll
    for (int j = 0; j < 13; ++j) {
        bf16x8 a1 = *(const bf16x8*)(Aus + 2 * (ap1 + 20 * j));
        bf16x8 a2 = *(const bf16x8*)(Aus + 2 * (ap2 + 20 * j));
        bf16x8 b  = ld_b_frag(bw + boff + 16 * j);
        acc1 = __builtin_amdgcn_mfma_f32_16x16x32_bf16(a1, b, acc1, 0, 0, 0);
        acc2 = __builtin_amdgcn_mfma_f32_16x16x32_bf16(a2, b, acc2, 0, 0, 0);
    }

    float ac0 = __shfl(acc1[0], 0);

    float bv = -1e30f; int bl = 1 << 30;
    #pragma unroll
    for (int r = 0; r < 4; ++r) {
        int lag = 64 * q + 16 * r + lo;
        float v = acc1[r];
        if (lag >= 32 && v > bv) { bv = v; bl = lag; }
    }
    if (q == 0) {
        #pragma unroll
        for (int r = 0; r < 4; ++r) {
            int lag = 256 + 16 * r + lo;
            float v = acc2[r];
            if (v > bv) { bv = v; bl = lag; }
        }
    }
    #pragma unroll
    for (int off = 32; off; off >>= 1) {
        float ov = __shfl_xor(bv, off);
        int   ol = __shfl_xor(bl, off);
        if (ov > bv || (ov == bv && ol < bl)) { bv = ov; bl = ol; }
    }

    if (lane == 0) {
        float f0 = SR_F / (float)bl;
        int valid = (bv > 0.3f * ac0) && (f0 > 50.f) && (f0 < 500.f);
        size_t idx = (size_t)s * NF + f_raw;
        ws[OFF_RMS + idx] = sqrtf(ss / (float)FRAME);
        ws[OFF_ZCR + idx] = zc / (2.f * (float)FRAME);
        ws[OFF_AMP + idx] = amp;
        ws[OFF_F0  + idx] = f0;
        ws[OFF_VAL + idx] = valid ? 1.f : 0.f;
        atomicMax((uint*)ws + OFF_MAX + s, __float_as_uint(amp));
    }
}

// ---------------------------------------------------------------------------
// K2b: crossing bitmask.  25 blocks/sample, ballot-packed to global.
// ---------------------------------------------------------------------------
__global__ __launch_bounds__(256) void k_cross(const float* __restrict__ audio,
                                               float* __restrict__ ws)
{
    const int s = blockIdx.y, b = blockIdx.x, tid = threadIdx.x;
    const float thr = 0.3f * __uint_as_float(((const uint*)ws)[OFF_MAX + s]);
    const float* a = audio + (size_t)s * NSAMP;
    unsigned long long* msk =
        (unsigned long long*)(ws + OFF_MSK) + (size_t)s * 2500 + (size_t)b * 100;
    const int base0 = b * 6400;
    #pragma unroll 5
    for (int it = 0; it < 25; ++it) {
        int i = base0 + it * 256 + tid;
        bool fl = (i < NSAMP - 1) && (a[i] < thr) && (a[i + 1] >= thr);
        unsigned long long bal = __ballot(fl);
        if ((tid & 63) == 0) msk[(it * 256 + tid) >> 6] = bal;
    }
}

// ---------------------------------------------------------------------------
// K2c: stitch — chunk states over the bitmask, associative merge.
// ---------------------------------------------------------------------------
__global__ __launch_bounds__(256) void k_jstitch(float* __restrict__ ws)
{
    __shared__ unsigned long long msk[2500];
    __shared__ int   s_cnt[256], s_p0[256], s_p1[256], s_pl[256], s_pl2[256];
    __shared__ float s_sum[256];
    const int s = blockIdx.x, tid = threadIdx.x;
    const unsigned long long* gm =
        (const unsigned long long*)(ws + OFF_MSK) + (size_t)s * 2500;
    for (int i = tid; i < 2500; i += 256) msk[i] = gm[i];
    __syncthreads();

    if (tid < 250) {
        int cnt = 0, p0 = 0, p1 = 0, pl = 0, pl2 = 0;
        float sum = 0.f;
        for (int wi = 0; wi < 10; ++wi) {
            unsigned long long word = msk[tid * 10 + wi];
            int wb = (tid * 10 + wi) << 6;
            while (word) {
                int b = __builtin_ctzll(word);
                word &= word - 1;
                int pos = wb + b + 1;
                if (cnt >= 2) sum += fabsf((float)((pos - pl) - (pl - pl2)));
                if (cnt == 0) p0 = pos;
                if (cnt == 1) p1 = pos;
                pl2 = pl; pl = pos; ++cnt;
            }
        }
        s_cnt[tid] = cnt; s_p0[tid] = p0; s_p1[tid] = p1;
        s_pl[tid] = pl; s_pl2[tid] = pl2; s_sum[tid] = sum;
    }
    __syncthreads();

    if (tid == 0) {
        int Ac = 0, Ap0 = 0, Ap1 = 0, Apl = 0, Apl2 = 0; float As = 0.f;
        for (int c = 0; c < 250; ++c) {
            int rc = s_cnt[c]; if (!rc) continue;
            int rp0 = s_p0[c], rp1 = s_p1[c], rpl = s_pl[c], rpl2 = s_pl2[c];
            float rs = s_sum[c];
            if (Ac == 0) { Ac = rc; Ap0 = rp0; Ap1 = rp1; Apl = rpl; Apl2 = rpl2; As = rs; continue; }
            int pb = rp0 - Apl;
            As += rs;
            if (Ac >= 2) As += fabsf((float)(pb - (Apl - Apl2)));
            if (rc >= 2) As += fabsf((float)((rp1 - rp0) - pb));
            if (Ac == 1) Ap1 = rp0;
            Apl2 = (rc >= 2) ? rpl2 : Apl;
            Apl = rpl;
            Ac += rc;
        }
        float* j = ws + OFF_JIT + s * 4;
        j[0] = (float)Ac; j[1] = (float)Ap0; j[2] = (float)Apl; j[3] = As;
    }
}

// ---------------------------------------------------------------------------
// K3: HNR partial autocorr via MFMA, lags 50..199 (as 48+16m+n).
// Per-wave LDS (dwords): A_pad [0,704) padded, xw [704,1280), xo [1280,1856).
// ---------------------------------------------------------------------------
__global__ __launch_bounds__(256) void k_hnr(const float* __restrict__ audio,
                                             float* __restrict__ ws)
{
    __shared__ __align__(16) uint lds[4][1856];
    const int tid = threadIdx.x;
    const int widx = tid >> 6, lane = tid & 63;
    const int lo = lane & 15, q = lane >> 4;
    const int s = blockIdx.y;
    const int c = blockIdx.x * 4 + widx;
    const float* a = audio + (size_t)s * NSAMP;

    uint* Ap = lds[widx];
    uint* xw = Ap + 704;
    uint* xo = Ap + 1280;

    const int aoff = 240 + 8 * q - 16 * lo;              // elems, mult of 8, >= 0
    const int apb = (aoff >> 1) + 4 * (aoff >> 5);       // padded dword base
    const uint* bw = (lo & 1) ? xo : xw;
    const int boff = 144 + 4 * q + (lo >> 1);
    const ushort* Aus = (const ushort*)Ap;

    f32x4 acc = {0.f, 0.f, 0.f, 0.f};

    for (int tile = 0; tile < JCH / TJ; ++tile) {
        const int g0 = 32 * (c * JCH + tile * TJ) - 288;
        for (int v = lane; v < HWIN / 4; v += 64) {
            int g = g0 + 4 * v;
            float x0, x1, x2, x3, x4;
            if (g >= 0 && g + 4 < NSAMP) {
                float4 t = *(const float4*)(a + g);
                x0 = t.x; x1 = t.y; x2 = t.z; x3 = t.w;
                x4 = a[g + 4];
            } else {
                x0 = (g     >= 0 && g     < NSAMP) ? a[g]     : 0.f;
                x1 = (g + 1 >= 0 && g + 1 < NSAMP) ? a[g + 1] : 0.f;
                x2 = (g + 2 >= 0 && g + 2 < NSAMP) ? a[g + 2] : 0.f;
                x3 = (g + 3 >= 0 && g + 3 < NSAMP) ? a[g + 3] : 0.f;
                x4 = (g + 4 >= 0 && g + 4 < NSAMP) ? a[g + 4] : 0.f;
            }
            uint w0 = pack_bf16(x0, x1), w1 = pack_bf16(x2, x3);
            uint o0 = pack_bf16(x1, x2), o1 = pack_bf16(x3, x4);
            int d = 2 * v;
            xw[d] = w0; xw[d + 1] = w1;
            xo[d] = o0; xo[d + 1] = o1;
            int pv = d + 4 * (d >> 4);
            Ap[pv] = w0; Ap[pv + 1] = w1;
        }
        // same-wave LDS in-order: no barrier needed (per-wave arrays)
        #pragma unroll
        for (int jl = 0; jl < TJ; ++jl) {
            bf16x8 af = *(const bf16x8*)(Aus + 2 * (apb + 20 * jl));
            bf16x8 bf = ld_b_frag(bw + boff + 16 * jl);
            acc = __builtin_amdgcn_mfma_f32_16x16x32_bf16(af, bf, acc, 0, 0, 0);
        }
    }

    #pragma unroll
    for (int r = 0; r < 4; ++r) {
        int row = 4 * q + r;
        int lag = 48 + 16 * row + lo;
        if (row < 10 && lag >= 50 && lag < 200)
            ws[OFF_HNR + ((size_t)s * NHNR_CHUNK + c) * HNR_LAGS + (lag - 50)] = acc[r];
    }
}

// ---------------------------------------------------------------------------
// K4: per-sample finalize + MLP
// ---------------------------------------------------------------------------
__global__ __launch_bounds__(256) void k_final(const float* __restrict__ ws,
        const float* __restrict__ W1, const float* __restrict__ b1,
        const float* __restrict__ gam, const float* __restrict__ bet,
        const float* __restrict__ W2, const float* __restrict__ b2,
        float* __restrict__ out)
{
    __shared__ float samp[NF];
    __shared__ float sac[HNR_LAGS];
    __shared__ float sred[32];
    __shared__ float sstat[12];
    __shared__ float sfeats[10];
    __shared__ float shid[64];

    const int s = blockIdx.x;
    const int tid = threadIdx.x;
    const float* rmsA = ws + OFF_RMS + (size_t)s * NF;
    const float* zcrA = ws + OFF_ZCR + (size_t)s * NF;
    const float* ampA = ws + OFF_AMP + (size_t)s * NF;
    const float* f0A  = ws + OFF_F0  + (size_t)s * NF;
    const float* valA = ws + OFF_VAL + (size_t)s * NF;

    float a0=0,a1=0,a2=0,a3=0,a4=0,a5=0,a6=0,a7=0;
    for (int i = tid; i < NF; i += 256) {
        float r = rmsA[i], z = zcrA[i], f0 = f0A[i], v = valA[i];
        samp[i] = ampA[i];
        a0 += r; a1 += r * r; a2 += z; a3 += z * z;
        a4 += f0 * v; a5 += f0 * f0 * v; a6 += v;
        a7 += (r > 0.01f && z < 0.3f) ? 1.f : 0.f;
    }
    #pragma unroll
    for (int off = 32; off; off >>= 1) {
        a0 += __shfl_xor(a0, off); a1 += __shfl_xor(a1, off);
        a2 += __shfl_xor(a2, off); a3 += __shfl_xor(a3, off);
        a4 += __shfl_xor(a4, off); a5 += __shfl_xor(a5, off);
        a6 += __shfl_xor(a6, off); a7 += __shfl_xor(a7, off);
    }
    if ((tid & 63) == 0) {
        int w = tid >> 6;
        sred[w*8+0]=a0; sred[w*8+1]=a1; sred[w*8+2]=a2; sred[w*8+3]=a3;
        sred[w*8+4]=a4; sred[w*8+5]=a5; sred[w*8+6]=a6; sred[w*8+7]=a7;
    }
    __syncthreads();

    if (tid < HNR_LAGS) {
        float acc = 0.f;
        const float* p = ws + OFF_HNR + (size_t)s * NHNR_CHUNK * HNR_LAGS + tid;
        for (int c = 0; c < NHNR_CHUNK; ++c) acc += p[c * HNR_LAGS];
        sac[tid] = acc;
    }
    if (tid == 0) {
        for (int k = 0; k < 8; ++k)
            sstat[k] = sred[k] + sred[8+k] + sred[16+k] + sred[24+k];
    }
    __syncthreads();

    if (tid < HNR_LAGS) {
        float v = sac[tid];
        int r = 0;
        for (int j = 0; j < HNR_LAGS; ++j) {
            float vj = sac[j];
            r += (vj < v) || (vj == v && j < tid);
        }
        if (r == 14) sstat[8] = v;
        if (r == 15) sstat[9] = v;
    }
    if (tid == 192) {
        float mx = sac[0];
        for (int j = 1; j < HNR_LAGS; ++j) mx = fmaxf(mx, sac[j]);
        sstat[10] = mx;
    }
    if (tid == 224) {
        int ka = 0; float sum_amp = 0.f, sum_ad = 0.f, prev = 0.f;
        for (int i = 0; i < NF; ++i) {
            float amp = samp[i];
            if (amp > 0.01f) {
                if (ka >= 1) sum_ad += fabsf(amp - prev);
                sum_amp += amp; prev = amp; ++ka;
            }
        }
        float mean_amp = sum_amp / (float)imax_(ka, 1);
        float mean_ad  = sum_ad  / (float)imax_(ka - 1, 1);
        sstat[11] = (ka >= 2 && mean_amp > 0.f)
            ? fminf(fmaxf(mean_ad / fmaxf(mean_amp, 1e-12f), 0.f), 1.f) : 0.f;
    }
    __syncthreads();

    if (tid == 0) {
        float S_r = sstat[0], S_r2 = sstat[1], S_z = sstat[2], S_z2 = sstat[3];
        float S_f = sstat[4], S_f2 = sstat[5], S_v = sstat[6], S_voi = sstat[7];
        float e_mean = S_r / (float)NF;
        float e_std  = sqrtf(fmaxf(S_r2 / (float)NF - e_mean * e_mean, 0.f));
        float z_mean = S_z / (float)NF;
        float z_std  = sqrtf(fmaxf(S_z2 / (float)NF - z_mean * z_mean, 0.f));
        float f0_mean = 0.f, f0_std = 0.f;
        if (S_v > 0.f) {
            f0_mean = S_f / S_v;
            f0_std  = sqrtf(fmaxf(S_f2 / S_v - f0_mean * f0_mean, 0.f));
        }
        const float* jp = ws + OFF_JIT + s * 4;
        int k = (int)jp[0];
        float pp0 = jp[1], ppl = jp[2], psum = jp[3];
        int nper = k - 1;
        float mean_period = (k >= 2) ? (ppl - pp0) / (float)(k - 1) : 0.f;
        float mean_pd = psum / (float)imax_(nper - 1, 1);
        float jit = (nper >= 2 && mean_period > 0.f)
            ? fminf(fmaxf(mean_pd / fmaxf(mean_period, 1e-12f), 0.f), 1.f) : 0.f;
        if (f0_mean < 50.f || f0_mean > 500.f) jit = 0.f;
        float noise = 0.1f * sstat[8] + 0.9f * sstat[9];
        float hnr = (noise > 0.f)
            ? fminf(fmaxf(sstat[10] / fmaxf(noise, 1e-30f) / 100.f, 0.f), 1.f) : 0.f;
        float shim = sstat[11];
        float voice = S_voi / (float)NF;

        float mt[10] = {f0_mean, f0_std, e_mean, e_std, z_mean, z_std, jit, shim, hnr, voice};
        for (int i = 0; i < 10; ++i) out[NB * 128 + s * 10 + i] = mt[i];
        sfeats[0] = f0_mean / 500.f;
        sfeats[1] = f0_std / 100.f;
        for (int i = 2; i < 10; ++i) sfeats[i] = mt[i];
    }
    __syncthreads();

    if (tid < 64) {
        float h = b1[tid];
        #pragma unroll
        for (int i = 0; i < 10; ++i) h = fmaf(sfeats[i], W1[tid * 10 + i], h);
        float sum = h, sq = h * h;
        #pragma unroll
        for (int off = 32; off; off >>= 1) {
            sum += __shfl_xor(sum, off);
            sq  += __shfl_xor(sq, off);
        }
        float mu = sum / 64.f;
        float var = sq / 64.f - mu * mu;
        float hn = (h - mu) * rsqrtf(var + 1e-5f) * gam[tid] + bet[tid];
        shid[tid] = fmaxf(hn, 0.f);
    }
    __syncthreads();
    if (tid < 128) {
        float accv = b2[tid];
        #pragma unroll 8
        for (int j = 0; j < 64; ++j) accv = fmaf(shid[j], W2[tid * 64 + j], accv);
        out[(size_t)s * 128 + tid] = accv;
    }
}

// ---------------------------------------------------------------------------
extern "C" void kernel_launch(void* const* d_in, const int* in_sizes, int n_in,
                              void* d_out, int out_size, void* d_ws, size_t ws_size,
                              hipStream_t stream)
{
    const float* audio = (const float*)d_in[0];
    const float* W1    = (const float*)d_in[1];
    const float* b1    = (const float*)d_in[2];
    const float* gam   = (const float*)d_in[3];
    const float* bet   = (const float*)d_in[4];
    const float* W2    = (const float*)d_in[5];
    const float* b2    = (const float*)d_in[6];
    float* out = (float*)d_out;
    float* ws  = (float*)d_ws;

    hipMemsetAsync((uint*)ws + OFF_MAX, 0, NB * sizeof(uint), stream);
    hipLaunchKernelGGL(k_frame,   dim3((NF + 3) / 4, NB),   dim3(256), 0, stream, audio, ws);
    hipLaunchKernelGGL(k_cross,   dim3(25, NB),             dim3(256), 0, stream, audio, ws);
    hipLaunchKernelGGL(k_jstitch, dim3(NB),                 dim3(256), 0, stream, ws);
    hipLaunchKernelGGL(k_hnr,     dim3(NHNR_CHUNK / 4, NB), dim3(256), 0, stream, audio, ws);
    hipLaunchKernelGGL(k_final,   dim3(NB),                 dim3(256), 0, stream,
                       ws, W1, b1, gam, bet, W2, b2, out);
}

// Round 6
// 936.546 us; speedup vs baseline: 1.1045x; 1.1045x over previous
//
#include <hip/hip_runtime.h>
#include <stdint.h>

typedef unsigned int uint;
typedef unsigned short ushort;
typedef __attribute__((ext_vector_type(8))) short bf16x8;
typedef __attribute__((ext_vector_type(4))) float f32x4;

#define SR_F 16000.0f
#define NSAMP 160000
#define NB 128
#define FRAME 400
#define HOP 160
#define NF 998
#define NHNR_CHUNK 40
#define JCH 125
#define HNR_LAGS 150
#define TJ 25
#define HWIN (32*TJ + 304)   // 1104 elems

// workspace layout (float offsets)
#define OFF_RMS 0
#define OFF_ZCR (OFF_RMS + NB*NF)
#define OFF_AMP (OFF_ZCR + NB*NF)
#define OFF_F0  (OFF_AMP + NB*NF)
#define OFF_VAL (OFF_F0  + NB*NF)
#define OFF_JIT (OFF_VAL + NB*NF)
#define OFF_HNR (OFF_JIT + NB*4)
#define OFF_MAX (OFF_HNR + NB*NHNR_CHUNK*HNR_LAGS)   // NB uints
#define OFF_MSK (OFF_MAX + NB)                       // NB*2500 u64

__device__ __forceinline__ int imax_(int a, int b) { return a > b ? a : b; }

__device__ __forceinline__ uint pack_bf16(float a, float b) {
    uint ua = __builtin_bit_cast(uint, a), ub = __builtin_bit_cast(uint, b);
    ua = (ua + 0x8000u) >> 16; ub = (ub + 0x8000u) >> 16;
    return ua | (ub << 16);
}

__device__ __forceinline__ bf16x8 ld_b_frag(const uint* p) {
    union { uint u[4]; bf16x8 v; } t;
    t.u[0] = p[0]; t.u[1] = p[1]; t.u[2] = p[2]; t.u[3] = p[3];
    return t.v;
}

__device__ __forceinline__ float sgn_(float v) {
    return (float)(v > 0.f) - (float)(v < 0.f);
}

// ---------------------------------------------------------------------------
// K1: per-frame stats + autocorr peak via MFMA.  4 waves/block, 1 frame/wave.
// Per-wave LDS (dwords): A_pad [0,576) padded (raw d -> d + 4*(d>>4); A-frag
// lane stride -8 raw dwords becomes -8/-12 -> <=2-way, free), xw [576,1088)
// shift-0 bf16 pairs, xo [1088,1576) shift-1.
// __syncthreads() after staging is a SCHEDULING FENCE: removing it lets the
// compiler interleave staging stores into the MFMA loop -> 5x regression (R5).
// Fused |a| max: per-frame amp atomicMax; tail [159920,160000) by blk0/wave0.
// f is clamped (not early-returned) so every wave reaches the barrier.
// ---------------------------------------------------------------------------
__global__ __launch_bounds__(256) void k_frame(const float* __restrict__ audio,
                                               float* __restrict__ ws)
{
    __shared__ __align__(16) uint lds[4][1576];
    const int tid = threadIdx.x;
    const int widx = tid >> 6, lane = tid & 63;
    const int lo = lane & 15, q = lane >> 4;
    const int s = blockIdx.y;
    int f = blockIdx.x * 4 + widx;
    const bool tail_wave = (blockIdx.x == 0 && widx == 0);
    if (f > NF - 1) f = NF - 1;          // dup last frame (identical writes, benign)
    const float* as = audio + (size_t)s * NSAMP;

    uint* Ap = lds[widx];
    uint* xw = Ap + 576;
    uint* xo = Ap + 1088;

    // zero whole per-wave region (pads/boundary zeros), then overwrite data
    {
        uint4 z; z.x = 0; z.y = 0; z.z = 0; z.w = 0;
        uint4* p = (uint4*)Ap;
        for (int i = lane; i < 394; i += 64) p[i] = z;
    }

    const float* a = as + (size_t)f * HOP;
    float ss = 0.f, zc = 0.f, amp = 0.f;
    for (int vi = lane; vi < 100; vi += 64) {
        float4 t = ((const float4*)a)[vi];
        float bn = (vi < 99) ? a[4 * vi + 4] : 0.f;
        ss += t.x * t.x + t.y * t.y + t.z * t.z + t.w * t.w;
        amp = fmaxf(amp, fmaxf(fmaxf(fabsf(t.x), fabsf(t.y)),
                               fmaxf(fabsf(t.z), fabsf(t.w))));
        zc += fabsf(sgn_(t.y) - sgn_(t.x)) + fabsf(sgn_(t.z) - sgn_(t.y))
            + fabsf(sgn_(t.w) - sgn_(t.z));
        if (vi < 99) zc += fabsf(sgn_(bn) - sgn_(t.w));
        uint w0 = pack_bf16(t.x, t.y), w1 = pack_bf16(t.z, t.w);
        uint o0 = pack_bf16(t.y, t.z), o1 = pack_bf16(t.w, bn);
        int d = 248 + 2 * vi;
        xw[d] = w0; xw[d + 1] = w1;
        xo[d] = o0; xo[d + 1] = o1;
        int pv = d + 4 * (d >> 4);
        Ap[pv] = w0; Ap[pv + 1] = w1;
    }
    #pragma unroll
    for (int off = 32; off; off >>= 1) {
        ss += __shfl_xor(ss, off);
        zc += __shfl_xor(zc, off);
        amp = fmaxf(amp, __shfl_xor(amp, off));
    }

    // tail absmax (samples not covered by any frame), one wave per sample s
    if (tail_wave) {
        float m = fabsf(as[159920 + lane]);
        if (lane < 16) m = fmaxf(m, fabsf(as[159984 + lane]));
        #pragma unroll
        for (int off = 32; off; off >>= 1) m = fmaxf(m, __shfl_xor(m, off));
        if (lane == 0)
            atomicMax((uint*)ws + OFF_MAX + s, __float_as_uint(m));
    }

    __syncthreads();   // scheduling fence: keep staging and MFMA loop apart

    f32x4 acc1 = {0.f, 0.f, 0.f, 0.f};
    f32x4 acc2 = {0.f, 0.f, 0.f, 0.f};
    const int aoff1 = 496 + 8 * q - 16 * lo;              // elems, mult of 8
    const int ap1 = (aoff1 >> 1) + 4 * (aoff1 >> 5);      // padded dword, mult of 4
    const int ap2 = ap1 - 160;                            // (aoff1-256) padded
    const uint* bw = (lo & 1) ? xo : xw;
    const int boff = 248 + 4 * q + (lo >> 1);
    const ushort* Aus = (const ushort*)Ap;

    #pragma unroll
    for (int j = 0; j < 13; ++j) {
        bf16x8 a1 = *(const bf16x8*)(Aus + 2 * (ap1 + 20 * j));
        bf16x8 a2 = *(const bf16x8*)(Aus + 2 * (ap2 + 20 * j));
        bf16x8 b  = ld_b_frag(bw + boff + 16 * j);
        acc1 = __builtin_amdgcn_mfma_f32_16x16x32_bf16(a1, b, acc1, 0, 0, 0);
        acc2 = __builtin_amdgcn_mfma_f32_16x16x32_bf16(a2, b, acc2, 0, 0, 0);
    }

    float ac0 = __shfl(acc1[0], 0);

    float bv = -1e30f; int bl = 1 << 30;
    #pragma unroll
    for (int r = 0; r < 4; ++r) {
        int lag = 64 * q + 16 * r + lo;
        float v = acc1[r];
        if (lag >= 32 && v > bv) { bv = v; bl = lag; }
    }
    if (q == 0) {
        #pragma unroll
        for (int r = 0; r < 4; ++r) {
            int lag = 256 + 16 * r + lo;
            float v = acc2[r];
            if (v > bv) { bv = v; bl = lag; }
        }
    }
    #pragma unroll
    for (int off = 32; off; off >>= 1) {
        float ov = __shfl_xor(bv, off);
        int   ol = __shfl_xor(bl, off);
        if (ov > bv || (ov == bv && ol < bl)) { bv = ov; bl = ol; }
    }

    if (lane == 0) {
        float f0 = SR_F / (float)bl;
        int valid = (bv > 0.3f * ac0) && (f0 > 50.f) && (f0 < 500.f);
        size_t idx = (size_t)s * NF + f;
        ws[OFF_RMS + idx] = sqrtf(ss / (float)FRAME);
        ws[OFF_ZCR + idx] = zc / (2.f * (float)FRAME);
        ws[OFF_AMP + idx] = amp;
        ws[OFF_F0  + idx] = f0;
        ws[OFF_VAL + idx] = valid ? 1.f : 0.f;
        atomicMax((uint*)ws + OFF_MAX + s, __float_as_uint(amp));
    }
}

// ---------------------------------------------------------------------------
// K2b: crossing bitmask.  25 blocks/sample, ballot-packed to global.
// ---------------------------------------------------------------------------
__global__ __launch_bounds__(256) void k_cross(const float* __restrict__ audio,
                                               float* __restrict__ ws)
{
    const int s = blockIdx.y, b = blockIdx.x, tid = threadIdx.x;
    const float thr = 0.3f * __uint_as_float(((const uint*)ws)[OFF_MAX + s]);
    const float* a = audio + (size_t)s * NSAMP;
    unsigned long long* msk =
        (unsigned long long*)(ws + OFF_MSK) + (size_t)s * 2500 + (size_t)b * 100;
    const int base0 = b * 6400;
    #pragma unroll 5
    for (int it = 0; it < 25; ++it) {
        int i = base0 + it * 256 + tid;
        bool fl = (i < NSAMP - 1) && (a[i] < thr) && (a[i + 1] >= thr);
        unsigned long long bal = __ballot(fl);
        if ((tid & 63) == 0) msk[(it * 256 + tid) >> 6] = bal;
    }
}

// ---------------------------------------------------------------------------
// K2c: stitch — chunk states over the bitmask, associative merge.
// ---------------------------------------------------------------------------
__global__ __launch_bounds__(256) void k_jstitch(float* __restrict__ ws)
{
    __shared__ unsigned long long msk[2500];
    __shared__ int   s_cnt[256], s_p0[256], s_p1[256], s_pl[256], s_pl2[256];
    __shared__ float s_sum[256];
    const int s = blockIdx.x, tid = threadIdx.x;
    const unsigned long long* gm =
        (const unsigned long long*)(ws + OFF_MSK) + (size_t)s * 2500;
    for (int i = tid; i < 2500; i += 256) msk[i] = gm[i];
    __syncthreads();

    if (tid < 250) {
        int cnt = 0, p0 = 0, p1 = 0, pl = 0, pl2 = 0;
        float sum = 0.f;
        for (int wi = 0; wi < 10; ++wi) {
            unsigned long long word = msk[tid * 10 + wi];
            int wb = (tid * 10 + wi) << 6;
            while (word) {
                int b = __builtin_ctzll(word);
                word &= word - 1;
                int pos = wb + b + 1;
                if (cnt >= 2) sum += fabsf((float)((pos - pl) - (pl - pl2)));
                if (cnt == 0) p0 = pos;
                if (cnt == 1) p1 = pos;
                pl2 = pl; pl = pos; ++cnt;
            }
        }
        s_cnt[tid] = cnt; s_p0[tid] = p0; s_p1[tid] = p1;
        s_pl[tid] = pl; s_pl2[tid] = pl2; s_sum[tid] = sum;
    }
    __syncthreads();

    if (tid == 0) {
        int Ac = 0, Ap0 = 0, Ap1 = 0, Apl = 0, Apl2 = 0; float As = 0.f;
        for (int c = 0; c < 250; ++c) {
            int rc = s_cnt[c]; if (!rc) continue;
            int rp0 = s_p0[c], rp1 = s_p1[c], rpl = s_pl[c], rpl2 = s_pl2[c];
            float rs = s_sum[c];
            if (Ac == 0) { Ac = rc; Ap0 = rp0; Ap1 = rp1; Apl = rpl; Apl2 = rpl2; As = rs; continue; }
            int pb = rp0 - Apl;
            As += rs;
            if (Ac >= 2) As += fabsf((float)(pb - (Apl - Apl2)));
            if (rc >= 2) As += fabsf((float)((rp1 - rp0) - pb));
            if (Ac == 1) Ap1 = rp0;
            Apl2 = (rc >= 2) ? rpl2 : Apl;
            Apl = rpl;
            Ac += rc;
        }
        float* j = ws + OFF_JIT + s * 4;
        j[0] = (float)Ac; j[1] = (float)Ap0; j[2] = (float)Apl; j[3] = As;
    }
}

// ---------------------------------------------------------------------------
// K3: HNR partial autocorr via MFMA, lags 50..199 (as 48+16m+n).
// Per-wave LDS (dwords): A_pad [0,704) padded, xw [704,1280), xo [1280,1856).
// Barriers around staging: scheduling fence (see k_frame comment / R5 lesson).
// ---------------------------------------------------------------------------
__global__ __launch_bounds__(256) void k_hnr(const float* __restrict__ audio,
                                             float* __restrict__ ws)
{
    __shared__ __align__(16) uint lds[4][1856];
    const int tid = threadIdx.x;
    const int widx = tid >> 6, lane = tid & 63;
    const int lo = lane & 15, q = lane >> 4;
    const int s = blockIdx.y;
    const int c = blockIdx.x * 4 + widx;
    const float* a = audio + (size_t)s * NSAMP;

    uint* Ap = lds[widx];
    uint* xw = Ap + 704;
    uint* xo = Ap + 1280;

    const int aoff = 240 + 8 * q - 16 * lo;              // elems, mult of 8, >= 0
    const int apb = (aoff >> 1) + 4 * (aoff >> 5);       // padded dword base
    const uint* bw = (lo & 1) ? xo : xw;
    const int boff = 144 + 4 * q + (lo >> 1);
    const ushort* Aus = (const ushort*)Ap;

    f32x4 acc = {0.f, 0.f, 0.f, 0.f};

    for (int tile = 0; tile < JCH / TJ; ++tile) {
        const int g0 = 32 * (c * JCH + tile * TJ) - 288;
        __syncthreads();
        for (int v = lane; v < HWIN / 4; v += 64) {
            int g = g0 + 4 * v;
            float x0, x1, x2, x3, x4;
            if (g >= 0 && g + 4 < NSAMP) {
                float4 t = *(const float4*)(a + g);
                x0 = t.x; x1 = t.y; x2 = t.z; x3 = t.w;
                x4 = a[g + 4];
            } else {
                x0 = (g     >= 0 && g     < NSAMP) ? a[g]     : 0.f;
                x1 = (g + 1 >= 0 && g + 1 < NSAMP) ? a[g + 1] : 0.f;
                x2 = (g + 2 >= 0 && g + 2 < NSAMP) ? a[g + 2] : 0.f;
                x3 = (g + 3 >= 0 && g + 3 < NSAMP) ? a[g + 3] : 0.f;
                x4 = (g + 4 >= 0 && g + 4 < NSAMP) ? a[g + 4] : 0.f;
            }
            uint w0 = pack_bf16(x0, x1), w1 = pack_bf16(x2, x3);
            uint o0 = pack_bf16(x1, x2), o1 = pack_bf16(x3, x4);
            int d = 2 * v;
            xw[d] = w0; xw[d + 1] = w1;
            xo[d] = o0; xo[d + 1] = o1;
            int pv = d + 4 * (d >> 4);
            Ap[pv] = w0; Ap[pv + 1] = w1;
        }
        __syncthreads();
        #pragma unroll
        for (int jl = 0; jl < TJ; ++jl) {
            bf16x8 af = *(const bf16x8*)(Aus + 2 * (apb + 20 * jl));
            bf16x8 bf = ld_b_frag(bw + boff + 16 * jl);
            acc = __builtin_amdgcn_mfma_f32_16x16x32_bf16(af, bf, acc, 0, 0, 0);
        }
    }

    #pragma unroll
    for (int r = 0; r < 4; ++r) {
        int row = 4 * q + r;
        int lag = 48 + 16 * row + lo;
        if (row < 10 && lag >= 50 && lag < 200)
            ws[OFF_HNR + ((size_t)s * NHNR_CHUNK + c) * HNR_LAGS + (lag - 50)] = acc[r];
    }
}

// ---------------------------------------------------------------------------
// K4: per-sample finalize + MLP
// ---------------------------------------------------------------------------
__global__ __launch_bounds__(256) void k_final(const float* __restrict__ ws,
        const float* __restrict__ W1, const float* __restrict__ b1,
        const float* __restrict__ gam, const float* __restrict__ bet,
        const float* __restrict__ W2, const float* __restrict__ b2,
        float* __restrict__ out)
{
    __shared__ float samp[NF];
    __shared__ float sac[HNR_LAGS];
    __shared__ float sred[32];
    __shared__ float sstat[12];
    __shared__ float sfeats[10];
    __shared__ float shid[64];

    const int s = blockIdx.x;
    const int tid = threadIdx.x;
    const float* rmsA = ws + OFF_RMS + (size_t)s * NF;
    const float* zcrA = ws + OFF_ZCR + (size_t)s * NF;
    const float* ampA = ws + OFF_AMP + (size_t)s * NF;
    const float* f0A  = ws + OFF_F0  + (size_t)s * NF;
    const float* valA = ws + OFF_VAL + (size_t)s * NF;

    float a0=0,a1=0,a2=0,a3=0,a4=0,a5=0,a6=0,a7=0;
    for (int i = tid; i < NF; i += 256) {
        float r = rmsA[i], z = zcrA[i], f0 = f0A[i], v = valA[i];
        samp[i] = ampA[i];
        a0 += r; a1 += r * r; a2 += z; a3 += z * z;
        a4 += f0 * v; a5 += f0 * f0 * v; a6 += v;
        a7 += (r > 0.01f && z < 0.3f) ? 1.f : 0.f;
    }
    #pragma unroll
    for (int off = 32; off; off >>= 1) {
        a0 += __shfl_xor(a0, off); a1 += __shfl_xor(a1, off);
        a2 += __shfl_xor(a2, off); a3 += __shfl_xor(a3, off);
        a4 += __shfl_xor(a4, off); a5 += __shfl_xor(a5, off);
        a6 += __shfl_xor(a6, off); a7 += __shfl_xor(a7, off);
    }
    if ((tid & 63) == 0) {
        int w = tid >> 6;
        sred[w*8+0]=a0; sred[w*8+1]=a1; sred[w*8+2]=a2; sred[w*8+3]=a3;
        sred[w*8+4]=a4; sred[w*8+5]=a5; sred[w*8+6]=a6; sred[w*8+7]=a7;
    }
    __syncthreads();

    if (tid < HNR_LAGS) {
        float acc = 0.f;
        const float* p = ws + OFF_HNR + (size_t)s * NHNR_CHUNK * HNR_LAGS + tid;
        for (int c = 0; c < NHNR_CHUNK; ++c) acc += p[c * HNR_LAGS];
        sac[tid] = acc;
    }
    if (tid == 0) {
        for (int k = 0; k < 8; ++k)
            sstat[k] = sred[k] + sred[8+k] + sred[16+k] + sred[24+k];
    }
    __syncthreads();

    if (tid < HNR_LAGS) {
        float v = sac[tid];
        int r = 0;
        for (int j = 0; j < HNR_LAGS; ++j) {
            float vj = sac[j];
            r += (vj < v) || (vj == v && j < tid);
        }
        if (r == 14) sstat[8] = v;
        if (r == 15) sstat[9] = v;
    }
    if (tid == 192) {
        float mx = sac[0];
        for (int j = 1; j < HNR_LAGS; ++j) mx = fmaxf(mx, sac[j]);
        sstat[10] = mx;
    }
    if (tid == 224) {
        int ka = 0; float sum_amp = 0.f, sum_ad = 0.f, prev = 0.f;
        for (int i = 0; i < NF; ++i) {
            float amp = samp[i];
            if (amp > 0.01f) {
                if (ka >= 1) sum_ad += fabsf(amp - prev);
                sum_amp += amp; prev = amp; ++ka;
            }
        }
        float mean_amp = sum_amp / (float)imax_(ka, 1);
        float mean_ad  = sum_ad  / (float)imax_(ka - 1, 1);
        sstat[11] = (ka >= 2 && mean_amp > 0.f)
            ? fminf(fmaxf(mean_ad / fmaxf(mean_amp, 1e-12f), 0.f), 1.f) : 0.f;
    }
    __syncthreads();

    if (tid == 0) {
        float S_r = sstat[0], S_r2 = sstat[1], S_z = sstat[2], S_z2 = sstat[3];
        float S_f = sstat[4], S_f2 = sstat[5], S_v = sstat[6], S_voi = sstat[7];
        float e_mean = S_r / (float)NF;
        float e_std  = sqrtf(fmaxf(S_r2 / (float)NF - e_mean * e_mean, 0.f));
        float z_mean = S_z / (float)NF;
        float z_std  = sqrtf(fmaxf(S_z2 / (float)NF - z_mean * z_mean, 0.f));
        float f0_mean = 0.f, f0_std = 0.f;
        if (S_v > 0.f) {
            f0_mean = S_f / S_v;
            f0_std  = sqrtf(fmaxf(S_f2 / S_v - f0_mean * f0_mean, 0.f));
        }
        const float* jp = ws + OFF_JIT + s * 4;
        int k = (int)jp[0];
        float pp0 = jp[1], ppl = jp[2], psum = jp[3];
        int nper = k - 1;
        float mean_period = (k >= 2) ? (ppl - pp0) / (float)(k - 1) : 0.f;
        float mean_pd = psum / (float)imax_(nper - 1, 1);
        float jit = (nper >= 2 && mean_period > 0.f)
            ? fminf(fmaxf(mean_pd / fmaxf(mean_period, 1e-12f), 0.f), 1.f) : 0.f;
        if (f0_mean < 50.f || f0_mean > 500.f) jit = 0.f;
        float noise = 0.1f * sstat[8] + 0.9f * sstat[9];
        float hnr = (noise > 0.f)
            ? fminf(fmaxf(sstat[10] / fmaxf(noise, 1e-30f) / 100.f, 0.f), 1.f) : 0.f;
        float shim = sstat[11];
        float voice = S_voi / (float)NF;

        float mt[10] = {f0_mean, f0_std, e_mean, e_std, z_mean, z_std, jit, shim, hnr, voice};
        for (int i = 0; i < 10; ++i) out[NB * 128 + s * 10 + i] = mt[i];
        sfeats[0] = f0_mean / 500.f;
        sfeats[1] = f0_std / 100.f;
        for (int i = 2; i < 10; ++i) sfeats[i] = mt[i];
    }
    __syncthreads();

    if (tid < 64) {
        float h = b1[tid];
        #pragma unroll
        for (int i = 0; i < 10; ++i) h = fmaf(sfeats[i], W1[tid * 10 + i], h);
        float sum = h, sq = h * h;
        #pragma unroll
        for (int off = 32; off; off >>= 1) {
            sum += __shfl_xor(sum, off);
            sq  += __shfl_xor(sq, off);
        }
        float mu = sum / 64.f;
        float var = sq / 64.f - mu * mu;
        float hn = (h - mu) * rsqrtf(var + 1e-5f) * gam[tid] + bet[tid];
        shid[tid] = fmaxf(hn, 0.f);
    }
    __syncthreads();
    if (tid < 128) {
        float accv = b2[tid];
        #pragma unroll 8
        for (int j = 0; j < 64; ++j) accv = fmaf(shid[j], W2[tid * 64 + j], accv);
        out[(size_t)s * 128 + tid] = accv;
    }
}

// ---------------------------------------------------------------------------
extern "C" void kernel_launch(void* const* d_in, const int* in_sizes, int n_in,
                              void* d_out, int out_size, void* d_ws, size_t ws_size,
                              hipStream_t stream)
{
    const float* audio = (const float*)d_in[0];
    const float* W1    = (const float*)d_in[1];
    const float* b1    = (const float*)d_in[2];
    const float* gam   = (const float*)d_in[3];
    const float* bet   = (const float*)d_in[4];
    const float* W2    = (const float*)d_in[5];
    const float* b2    = (const float*)d_in[6];
    float* out = (float*)d_out;
    float* ws  = (float*)d_ws;

    hipMemsetAsync((uint*)ws + OFF_MAX, 0, NB * sizeof(uint), stream);
    hipLaunchKernelGGL(k_frame,   dim3((NF + 3) / 4, NB),   dim3(256), 0, stream, audio, ws);
    hipLaunchKernelGGL(k_cross,   dim3(25, NB),             dim3(256), 0, stream, audio, ws);
    hipLaunchKernelGGL(k_jstitch, dim3(NB),                 dim3(256), 0, stream, ws);
    hipLaunchKernelGGL(k_hnr,     dim3(NHNR_CHUNK / 4, NB), dim3(256), 0, stream, audio, ws);
    hipLaunchKernelGGL(k_final,   dim3(NB),                 dim3(256), 0, stream,
                       ws, W1, b1, gam, bet, W2, b2, out);
}

// Round 7
// 453.386 us; speedup vs baseline: 2.2815x; 2.0657x over previous
//
#include <hip/hip_runtime.h>
#include <stdint.h>

typedef unsigned int uint;
typedef unsigned short ushort;
typedef __attribute__((ext_vector_type(8))) short bf16x8;
typedef __attribute__((ext_vector_type(4))) float f32x4;

#define SR_F 16000.0f
#define NSAMP 160000
#define NB 128
#define FRAME 400
#define HOP 160
#define NF 998
#define NHNR_CHUNK 40
#define JCH 125
#define HNR_LAGS 150
#define TJ 25
#define HWIN (32*TJ + 304)   // 1104 elems

// workspace layout (float offsets)
#define OFF_RMS 0
#define OFF_ZCR (OFF_RMS + NB*NF)
#define OFF_AMP (OFF_ZCR + NB*NF)
#define OFF_F0  (OFF_AMP + NB*NF)
#define OFF_VAL (OFF_F0  + NB*NF)
#define OFF_JIT (OFF_VAL + NB*NF)
#define OFF_HNR (OFF_JIT + NB*4)
#define OFF_MAX (OFF_HNR + NB*NHNR_CHUNK*HNR_LAGS)   // NB uints
#define OFF_MSK (OFF_MAX + NB)                       // NB*2500 u64

__device__ __forceinline__ int imax_(int a, int b) { return a > b ? a : b; }

__device__ __forceinline__ uint pack_bf16(float a, float b) {
    uint ua = __builtin_bit_cast(uint, a), ub = __builtin_bit_cast(uint, b);
    ua = (ua + 0x8000u) >> 16; ub = (ub + 0x8000u) >> 16;
    return ua | (ub << 16);
}

__device__ __forceinline__ bf16x8 ld_b_frag(const uint* p) {
    union { uint u[4]; bf16x8 v; } t;
    t.u[0] = p[0]; t.u[1] = p[1]; t.u[2] = p[2]; t.u[3] = p[3];
    return t.v;
}

__device__ __forceinline__ float sgn_(float v) {
    return (float)(v > 0.f) - (float)(v < 0.f);
}

// ---------------------------------------------------------------------------
// K1: per-frame stats + autocorr peak via MFMA.  4 waves/block, 4 frames/wave
// (sequential) with register prefetch of frame p+1 issued AFTER the barrier
// so the barrier's implicit vmcnt(0) drain never waits on it; the loads land
// during frame p's MFMA+epilogue (~1000 cyc) hiding HBM/L2 latency.
// LESSONS (R5/R6): no per-frame global atomics (128k device-scope atomics on
// 8 cache lines serialized the whole kernel 4x); no padded-A LDS layout
// (raised SQ_LDS_BANK_CONFLICT 2.6x); keep the staging->MFMA barrier.
// Per-wave LDS: xw (shift-0) / xo (shift-1) bf16 copies, 496-elem zero left
// pad + 400 data + 64 zero right pad = 960 elems each.
// ---------------------------------------------------------------------------
__global__ __launch_bounds__(256) void k_frame(const float* __restrict__ audio,
                                               float* __restrict__ ws)
{
    __shared__ __align__(16) ushort sx[4][2][960];
    const int tid = threadIdx.x;
    const int widx = tid >> 6, lane = tid & 63;
    const int lo = lane & 15, q = lane >> 4;
    const int s = blockIdx.y;
    const int fbase = blockIdx.x * 16 + widx * 4;
    const float* as = audio + (size_t)s * NSAMP;

    ushort* xw = &sx[widx][0][0];
    ushort* xo = &sx[widx][1][0];
    uint* xwd = (uint*)xw;
    uint* xod = (uint*)xo;

    // zero pads once: dwords [0,248) and [448,480), both copies
    {
        uint4 z; z.x = 0; z.y = 0; z.z = 0; z.w = 0;
        for (int i = lane; i < 70; i += 64) {
            int d = (i < 62) ? (i * 4) : (448 + (i - 62) * 4);
            *(uint4*)(xwd + d) = z;
            *(uint4*)(xod + d) = z;
        }
    }

    // prefetch frame p=0
    float4 tA, tB; float bnA, bnB;
    {
        int f0 = fbase; if (f0 > NF - 1) f0 = NF - 1;
        const float* a = as + (size_t)f0 * HOP;
        tA  = ((const float4*)a)[lane];
        bnA = a[4 * lane + 4];
        tB.x = tB.y = tB.z = tB.w = 0.f; bnB = 0.f;
        if (lane < 36) {
            tB  = ((const float4*)a)[64 + lane];
            bnB = (lane < 35) ? a[4 * (64 + lane) + 4] : 0.f;
        }
    }

    for (int p = 0; p < 4; ++p) {
        int f = fbase + p; if (f > NF - 1) f = NF - 1;  // dup writes benign

        // ---- stats + pack current regs into LDS (batch A: vi=lane) ----
        float ss, zc, amp;
        {
            ss  = tA.x*tA.x + tA.y*tA.y + tA.z*tA.z + tA.w*tA.w;
            amp = fmaxf(fmaxf(fabsf(tA.x), fabsf(tA.y)),
                        fmaxf(fabsf(tA.z), fabsf(tA.w)));
            zc  = fabsf(sgn_(tA.y) - sgn_(tA.x)) + fabsf(sgn_(tA.z) - sgn_(tA.y))
                + fabsf(sgn_(tA.w) - sgn_(tA.z)) + fabsf(sgn_(bnA) - sgn_(tA.w));
            int d = 248 + 2 * lane;
            xwd[d] = pack_bf16(tA.x, tA.y); xwd[d + 1] = pack_bf16(tA.z, tA.w);
            xod[d] = pack_bf16(tA.y, tA.z); xod[d + 1] = pack_bf16(tA.w, bnA);
        }
        if (lane < 36) {  // batch B: vi = 64+lane
            ss += tB.x*tB.x + tB.y*tB.y + tB.z*tB.z + tB.w*tB.w;
            amp = fmaxf(amp, fmaxf(fmaxf(fabsf(tB.x), fabsf(tB.y)),
                                   fmaxf(fabsf(tB.z), fabsf(tB.w))));
            zc += fabsf(sgn_(tB.y) - sgn_(tB.x)) + fabsf(sgn_(tB.z) - sgn_(tB.y))
                + fabsf(sgn_(tB.w) - sgn_(tB.z));
            if (lane < 35) zc += fabsf(sgn_(bnB) - sgn_(tB.w));
            int d = 376 + 2 * lane;
            xwd[d] = pack_bf16(tB.x, tB.y); xwd[d + 1] = pack_bf16(tB.z, tB.w);
            xod[d] = pack_bf16(tB.y, tB.z); xod[d + 1] = pack_bf16(tB.w, bnB);
        }
        #pragma unroll
        for (int off = 32; off; off >>= 1) {
            ss += __shfl_xor(ss, off);
            zc += __shfl_xor(zc, off);
            amp = fmaxf(amp, __shfl_xor(amp, off));
        }

        __syncthreads();   // fence: staging drained; prefetch issued BELOW

        // ---- prefetch frame p+1 (lands during MFMA) ----
        float4 nA, nB; float nbA = 0.f, nbB = 0.f;
        nA.x = nA.y = nA.z = nA.w = 0.f; nB = nA;
        if (p < 3) {
            int fn = fbase + p + 1; if (fn > NF - 1) fn = NF - 1;
            const float* an = as + (size_t)fn * HOP;
            nA  = ((const float4*)an)[lane];
            nbA = an[4 * lane + 4];
            if (lane < 36) {
                nB  = ((const float4*)an)[64 + lane];
                nbB = (lane < 35) ? an[4 * (64 + lane) + 4] : 0.f;
            }
        }

        // ---- MFMA K-loop ----
        f32x4 acc1 = {0.f, 0.f, 0.f, 0.f};
        f32x4 acc2 = {0.f, 0.f, 0.f, 0.f};
        const int aoff1 = 496 + 8 * q - 16 * lo;
        const int aoff2 = aoff1 - 256;
        const uint* bw = (lo & 1) ? xod : xwd;
        const int boff = 248 + 4 * q + (lo >> 1);

        #pragma unroll
        for (int j = 0; j < 13; ++j) {
            bf16x8 a1 = *(const bf16x8*)(xw + aoff1 + 32 * j);
            bf16x8 a2 = *(const bf16x8*)(xw + aoff2 + 32 * j);
            bf16x8 b  = ld_b_frag(bw + boff + 16 * j);
            acc1 = __builtin_amdgcn_mfma_f32_16x16x32_bf16(a1, b, acc1, 0, 0, 0);
            acc2 = __builtin_amdgcn_mfma_f32_16x16x32_bf16(a2, b, acc2, 0, 0, 0);
        }

        float ac0 = __shfl(acc1[0], 0);

        float bv = -1e30f; int bl = 1 << 30;
        #pragma unroll
        for (int r = 0; r < 4; ++r) {
            int lag = 64 * q + 16 * r + lo;
            float v = acc1[r];
            if (lag >= 32 && v > bv) { bv = v; bl = lag; }
        }
        if (q == 0) {
            #pragma unroll
            for (int r = 0; r < 4; ++r) {
                int lag = 256 + 16 * r + lo;
                float v = acc2[r];
                if (v > bv) { bv = v; bl = lag; }
            }
        }
        #pragma unroll
        for (int off = 32; off; off >>= 1) {
            float ov = __shfl_xor(bv, off);
            int   ol = __shfl_xor(bl, off);
            if (ov > bv || (ov == bv && ol < bl)) { bv = ov; bl = ol; }
        }

        if (lane == 0) {
            float f0v = SR_F / (float)bl;
            int valid = (bv > 0.3f * ac0) && (f0v > 50.f) && (f0v < 500.f);
            size_t idx = (size_t)s * NF + f;
            ws[OFF_RMS + idx] = sqrtf(ss / (float)FRAME);
            ws[OFF_ZCR + idx] = zc / (2.f * (float)FRAME);
            ws[OFF_AMP + idx] = amp;
            ws[OFF_F0  + idx] = f0v;
            ws[OFF_VAL + idx] = valid ? 1.f : 0.f;
        }

        tA = nA; tB = nB; bnA = nbA; bnB = nbB;
    }
}

// ---------------------------------------------------------------------------
// K2a: |a| max per sample.  20 blocks/sample, atomicMax on monotone uint bits.
// (Kept SEPARATE: fusing per-frame atomics into k_frame caused the R5/R6 4x
//  regression via cross-XCD atomic serialization — only 2560 atomics here.)
// ---------------------------------------------------------------------------
__global__ __launch_bounds__(256) void k_absmax(const float* __restrict__ audio,
                                                float* __restrict__ ws)
{
    __shared__ float sred[4];
    const int s = blockIdx.y, b = blockIdx.x, tid = threadIdx.x;
    const float4* a = (const float4*)(audio + (size_t)s * NSAMP) + (size_t)b * 2000;
    float m = 0.f;
    for (int i = tid; i < 2000; i += 256) {
        float4 t = a[i];
        m = fmaxf(m, fmaxf(fmaxf(fabsf(t.x), fabsf(t.y)),
                           fmaxf(fabsf(t.z), fabsf(t.w))));
    }
    #pragma unroll
    for (int off = 32; off; off >>= 1) m = fmaxf(m, __shfl_xor(m, off));
    if ((tid & 63) == 0) sred[tid >> 6] = m;
    __syncthreads();
    if (tid == 0) {
        float mm = fmaxf(fmaxf(sred[0], sred[1]), fmaxf(sred[2], sred[3]));
        atomicMax((uint*)ws + OFF_MAX + s, __float_as_uint(mm));
    }
}

// ---------------------------------------------------------------------------
// K2b: crossing bitmask.  25 blocks/sample, ballot-packed to global.
// ---------------------------------------------------------------------------
__global__ __launch_bounds__(256) void k_cross(const float* __restrict__ audio,
                                               float* __restrict__ ws)
{
    const int s = blockIdx.y, b = blockIdx.x, tid = threadIdx.x;
    const float thr = 0.3f * __uint_as_float(((const uint*)ws)[OFF_MAX + s]);
    const float* a = audio + (size_t)s * NSAMP;
    unsigned long long* msk =
        (unsigned long long*)(ws + OFF_MSK) + (size_t)s * 2500 + (size_t)b * 100;
    const int base0 = b * 6400;
    #pragma unroll 5
    for (int it = 0; it < 25; ++it) {
        int i = base0 + it * 256 + tid;
        bool fl = (i < NSAMP - 1) && (a[i] < thr) && (a[i + 1] >= thr);
        unsigned long long bal = __ballot(fl);
        if ((tid & 63) == 0) msk[(it * 256 + tid) >> 6] = bal;
    }
}

// ---------------------------------------------------------------------------
// K2c: stitch — chunk states over the bitmask, associative merge.
// ---------------------------------------------------------------------------
__global__ __launch_bounds__(256) void k_jstitch(float* __restrict__ ws)
{
    __shared__ unsigned long long msk[2500];
    __shared__ int   s_cnt[256], s_p0[256], s_p1[256], s_pl[256], s_pl2[256];
    __shared__ float s_sum[256];
    const int s = blockIdx.x, tid = threadIdx.x;
    const unsigned long long* gm =
        (const unsigned long long*)(ws + OFF_MSK) + (size_t)s * 2500;
    for (int i = tid; i < 2500; i += 256) msk[i] = gm[i];
    __syncthreads();

    if (tid < 250) {
        int cnt = 0, p0 = 0, p1 = 0, pl = 0, pl2 = 0;
        float sum = 0.f;
        for (int wi = 0; wi < 10; ++wi) {
            unsigned long long word = msk[tid * 10 + wi];
            int wb = (tid * 10 + wi) << 6;
            while (word) {
                int b = __builtin_ctzll(word);
                word &= word - 1;
                int pos = wb + b + 1;
                if (cnt >= 2) sum += fabsf((float)((pos - pl) - (pl - pl2)));
                if (cnt == 0) p0 = pos;
                if (cnt == 1) p1 = pos;
                pl2 = pl; pl = pos; ++cnt;
            }
        }
        s_cnt[tid] = cnt; s_p0[tid] = p0; s_p1[tid] = p1;
        s_pl[tid] = pl; s_pl2[tid] = pl2; s_sum[tid] = sum;
    }
    __syncthreads();

    if (tid == 0) {
        int Ac = 0, Ap0 = 0, Ap1 = 0, Apl = 0, Apl2 = 0; float As = 0.f;
        for (int c = 0; c < 250; ++c) {
            int rc = s_cnt[c]; if (!rc) continue;
            int rp0 = s_p0[c], rp1 = s_p1[c], rpl = s_pl[c], rpl2 = s_pl2[c];
            float rs = s_sum[c];
            if (Ac == 0) { Ac = rc; Ap0 = rp0; Ap1 = rp1; Apl = rpl; Apl2 = rpl2; As = rs; continue; }
            int pb = rp0 - Apl;
            As += rs;
            if (Ac >= 2) As += fabsf((float)(pb - (Apl - Apl2)));
            if (rc >= 2) As += fabsf((float)((rp1 - rp0) - pb));
            if (Ac == 1) Ap1 = rp0;
            Apl2 = (rc >= 2) ? rpl2 : Apl;
            Apl = rpl;
            Ac += rc;
        }
        float* j = ws + OFF_JIT + s * 4;
        j[0] = (float)Ac; j[1] = (float)Ap0; j[2] = (float)Apl; j[3] = As;
    }
}

// ---------------------------------------------------------------------------
// K3: HNR partial autocorr via MFMA, lags 50..199 (as 48+16m+n).  R4 layout.
// ---------------------------------------------------------------------------
__global__ __launch_bounds__(256) void k_hnr(const float* __restrict__ audio,
                                             float* __restrict__ ws)
{
    __shared__ __align__(16) ushort hx[4][2][HWIN];
    const int tid = threadIdx.x;
    const int widx = tid >> 6, lane = tid & 63;
    const int lo = lane & 15, q = lane >> 4;
    const int s = blockIdx.y;
    const int c = blockIdx.x * 4 + widx;
    const float* a = audio + (size_t)s * NSAMP;

    ushort* xw = &hx[widx][0][0];
    ushort* xo = &hx[widx][1][0];
    uint* xwd = (uint*)xw;
    uint* xod = (uint*)xo;

    const int aoff = 240 + 8 * q - 16 * lo;
    const uint* bw = (lo & 1) ? xod : xwd;
    const int boff = 144 + 4 * q + (lo >> 1);

    f32x4 acc = {0.f, 0.f, 0.f, 0.f};

    for (int tile = 0; tile < JCH / TJ; ++tile) {
        const int g0 = 32 * (c * JCH + tile * TJ) - 288;
        __syncthreads();
        for (int v = lane; v < HWIN / 4; v += 64) {
            int g = g0 + 4 * v;
            float x0, x1, x2, x3, x4;
            if (g >= 0 && g + 4 < NSAMP) {
                float4 t = *(const float4*)(a + g);
                x0 = t.x; x1 = t.y; x2 = t.z; x3 = t.w;
                x4 = a[g + 4];
            } else {
                x0 = (g     >= 0 && g     < NSAMP) ? a[g]     : 0.f;
                x1 = (g + 1 >= 0 && g + 1 < NSAMP) ? a[g + 1] : 0.f;
                x2 = (g + 2 >= 0 && g + 2 < NSAMP) ? a[g + 2] : 0.f;
                x3 = (g + 3 >= 0 && g + 3 < NSAMP) ? a[g + 3] : 0.f;
                x4 = (g + 4 >= 0 && g + 4 < NSAMP) ? a[g + 4] : 0.f;
            }
            int d = 2 * v;
            xwd[d] = pack_bf16(x0, x1); xwd[d + 1] = pack_bf16(x2, x3);
            xod[d] = pack_bf16(x1, x2); xod[d + 1] = pack_bf16(x3, x4);
        }
        __syncthreads();

        #pragma unroll
        for (int jl = 0; jl < TJ; ++jl) {
            bf16x8 af = *(const bf16x8*)(xw + aoff + 32 * jl);
            bf16x8 bf = ld_b_frag(bw + boff + 16 * jl);
            acc = __builtin_amdgcn_mfma_f32_16x16x32_bf16(af, bf, acc, 0, 0, 0);
        }
    }

    #pragma unroll
    for (int r = 0; r < 4; ++r) {
        int row = 4 * q + r;
        int lag = 48 + 16 * row + lo;
        if (row < 10 && lag >= 50 && lag < 200)
            ws[OFF_HNR + ((size_t)s * NHNR_CHUNK + c) * HNR_LAGS + (lag - 50)] = acc[r];
    }
}

// ---------------------------------------------------------------------------
// K4: per-sample finalize + MLP
// ---------------------------------------------------------------------------
__global__ __launch_bounds__(256) void k_final(const float* __restrict__ ws,
        const float* __restrict__ W1, const float* __restrict__ b1,
        const float* __restrict__ gam, const float* __restrict__ bet,
        const float* __restrict__ W2, const float* __restrict__ b2,
        float* __restrict__ out)
{
    __shared__ float samp[NF];
    __shared__ float sac[HNR_LAGS];
    __shared__ float sred[32];
    __shared__ float sstat[12];
    __shared__ float sfeats[10];
    __shared__ float shid[64];

    const int s = blockIdx.x;
    const int tid = threadIdx.x;
    const float* rmsA = ws + OFF_RMS + (size_t)s * NF;
    const float* zcrA = ws + OFF_ZCR + (size_t)s * NF;
    const float* ampA = ws + OFF_AMP + (size_t)s * NF;
    const float* f0A  = ws + OFF_F0  + (size_t)s * NF;
    const float* valA = ws + OFF_VAL + (size_t)s * NF;

    float a0=0,a1=0,a2=0,a3=0,a4=0,a5=0,a6=0,a7=0;
    for (int i = tid; i < NF; i += 256) {
        float r = rmsA[i], z = zcrA[i], f0 = f0A[i], v = valA[i];
        samp[i] = ampA[i];
        a0 += r; a1 += r * r; a2 += z; a3 += z * z;
        a4 += f0 * v; a5 += f0 * f0 * v; a6 += v;
        a7 += (r > 0.01f && z < 0.3f) ? 1.f : 0.f;
    }
    #pragma unroll
    for (int off = 32; off; off >>= 1) {
        a0 += __shfl_xor(a0, off); a1 += __shfl_xor(a1, off);
        a2 += __shfl_xor(a2, off); a3 += __shfl_xor(a3, off);
        a4 += __shfl_xor(a4, off); a5 += __shfl_xor(a5, off);
        a6 += __shfl_xor(a6, off); a7 += __shfl_xor(a7, off);
    }
    if ((tid & 63) == 0) {
        int w = tid >> 6;
        sred[w*8+0]=a0; sred[w*8+1]=a1; sred[w*8+2]=a2; sred[w*8+3]=a3;
        sred[w*8+4]=a4; sred[w*8+5]=a5; sred[w*8+6]=a6; sred[w*8+7]=a7;
    }
    __syncthreads();

    if (tid < HNR_LAGS) {
        float acc = 0.f;
        const float* p = ws + OFF_HNR + (size_t)s * NHNR_CHUNK * HNR_LAGS + tid;
        for (int c = 0; c < NHNR_CHUNK; ++c) acc += p[c * HNR_LAGS];
        sac[tid] = acc;
    }
    if (tid == 0) {
        for (int k = 0; k < 8; ++k)
            sstat[k] = sred[k] + sred[8+k] + sred[16+k] + sred[24+k];
    }
    __syncthreads();

    if (tid < HNR_LAGS) {
        float v = sac[tid];
        int r = 0;
        for (int j = 0; j < HNR_LAGS; ++j) {
            float vj = sac[j];
            r += (vj < v) || (vj == v && j < tid);
        }
        if (r == 14) sstat[8] = v;
        if (r == 15) sstat[9] = v;
    }
    if (tid == 192) {
        float mx = sac[0];
        for (int j = 1; j < HNR_LAGS; ++j) mx = fmaxf(mx, sac[j]);
        sstat[10] = mx;
    }
    if (tid == 224) {
        int ka = 0; float sum_amp = 0.f, sum_ad = 0.f, prev = 0.f;
        for (int i = 0; i < NF; ++i) {
            float amp = samp[i];
            if (amp > 0.01f) {
                if (ka >= 1) sum_ad += fabsf(amp - prev);
                sum_amp += amp; prev = amp; ++ka;
            }
        }
        float mean_amp = sum_amp / (float)imax_(ka, 1);
        float mean_ad  = sum_ad  / (float)imax_(ka - 1, 1);
        sstat[11] = (ka >= 2 && mean_amp > 0.f)
            ? fminf(fmaxf(mean_ad / fmaxf(mean_amp, 1e-12f), 0.f), 1.f) : 0.f;
    }
    __syncthreads();

    if (tid == 0) {
        float S_r = sstat[0], S_r2 = sstat[1], S_z = sstat[2], S_z2 = sstat[3];
        float S_f = sstat[4], S_f2 = sstat[5], S_v = sstat[6], S_voi = sstat[7];
        float e_mean = S_r / (float)NF;
        float e_std  = sqrtf(fmaxf(S_r2 / (float)NF - e_mean * e_mean, 0.f));
        float z_mean = S_z / (float)NF;
        float z_std  = sqrtf(fmaxf(S_z2 / (float)NF - z_mean * z_mean, 0.f));
        float f0_mean = 0.f, f0_std = 0.f;
        if (S_v > 0.f) {
            f0_mean = S_f / S_v;
            f0_std  = sqrtf(fmaxf(S_f2 / S_v - f0_mean * f0_mean, 0.f));
        }
        const float* jp = ws + OFF_JIT + s * 4;
        int k = (int)jp[0];
        float pp0 = jp[1], ppl = jp[2], psum = jp[3];
        int nper = k - 1;
        float mean_period = (k >= 2) ? (ppl - pp0) / (float)(k - 1) : 0.f;
        float mean_pd = psum / (float)imax_(nper - 1, 1);
        float jit = (nper >= 2 && mean_period > 0.f)
            ? fminf(fmaxf(mean_pd / fmaxf(mean_period, 1e-12f), 0.f), 1.f) : 0.f;
        if (f0_mean < 50.f || f0_mean > 500.f) jit = 0.f;
        float noise = 0.1f * sstat[8] + 0.9f * sstat[9];
        float hnr = (noise > 0.f)
            ? fminf(fmaxf(sstat[10] / fmaxf(noise, 1e-30f) / 100.f, 0.f), 1.f) : 0.f;
        float shim = sstat[11];
        float voice = S_voi / (float)NF;

        float mt[10] = {f0_mean, f0_std, e_mean, e_std, z_mean, z_std, jit, shim, hnr, voice};
        for (int i = 0; i < 10; ++i) out[NB * 128 + s * 10 + i] = mt[i];
        sfeats[0] = f0_mean / 500.f;
        sfeats[1] = f0_std / 100.f;
        for (int i = 2; i < 10; ++i) sfeats[i] = mt[i];
    }
    __syncthreads();

    if (tid < 64) {
        float h = b1[tid];
        #pragma unroll
        for (int i = 0; i < 10; ++i) h = fmaf(sfeats[i], W1[tid * 10 + i], h);
        float sum = h, sq = h * h;
        #pragma unroll
        for (int off = 32; off; off >>= 1) {
            sum += __shfl_xor(sum, off);
            sq  += __shfl_xor(sq, off);
        }
        float mu = sum / 64.f;
        float var = sq / 64.f - mu * mu;
        float hn = (h - mu) * rsqrtf(var + 1e-5f) * gam[tid] + bet[tid];
        shid[tid] = fmaxf(hn, 0.f);
    }
    __syncthreads();
    if (tid < 128) {
        float accv = b2[tid];
        #pragma unroll 8
        for (int j = 0; j < 64; ++j) accv = fmaf(shid[j], W2[tid * 64 + j], accv);
        out[(size_t)s * 128 + tid] = accv;
    }
}

// ---------------------------------------------------------------------------
extern "C" void kernel_launch(void* const* d_in, const int* in_sizes, int n_in,
                              void* d_out, int out_size, void* d_ws, size_t ws_size,
                              hipStream_t stream)
{
    const float* audio = (const float*)d_in[0];
    const float* W1    = (const float*)d_in[1];
    const float* b1    = (const float*)d_in[2];
    const float* gam   = (const float*)d_in[3];
    const float* bet   = (const float*)d_in[4];
    const float* W2    = (const float*)d_in[5];
    const float* b2    = (const float*)d_in[6];
    float* out = (float*)d_out;
    float* ws  = (float*)d_ws;

    hipMemsetAsync((uint*)ws + OFF_MAX, 0, NB * sizeof(uint), stream);
    hipLaunchKernelGGL(k_frame,   dim3((NF + 15) / 16, NB), dim3(256), 0, stream, audio, ws);
    hipLaunchKernelGGL(k_absmax,  dim3(20, NB),             dim3(256), 0, stream, audio, ws);
    hipLaunchKernelGGL(k_cross,   dim3(25, NB),             dim3(256), 0, stream, audio, ws);
    hipLaunchKernelGGL(k_jstitch, dim3(NB),                 dim3(256), 0, stream, ws);
    hipLaunchKernelGGL(k_hnr,     dim3(NHNR_CHUNK / 4, NB), dim3(256), 0, stream, audio, ws);
    hipLaunchKernelGGL(k_final,   dim3(NB),                 dim3(256), 0, stream,
                       ws, W1, b1, gam, bet, W2, b2, out);
}

// Round 8
// 421.729 us; speedup vs baseline: 2.4528x; 1.0751x over previous
//
#include <hip/hip_runtime.h>
#include <stdint.h>

typedef unsigned int uint;
typedef unsigned short ushort;
typedef unsigned long long ull;
typedef __attribute__((ext_vector_type(8))) short bf16x8;
typedef __attribute__((ext_vector_type(4))) float f32x4;

#define SR_F 16000.0f
#define NSAMP 160000
#define NB 128
#define FRAME 400
#define HOP 160
#define NF 998
#define NHNR_CHUNK 40
#define JCH 125
#define HNR_LAGS 150
#define TJ 25
#define HWIN (32*TJ + 304)   // 1104 elems

// workspace layout (float offsets)
#define OFF_RMS 0
#define OFF_ZCR (OFF_RMS + NB*NF)
#define OFF_AMP (OFF_ZCR + NB*NF)
#define OFF_F0  (OFF_AMP + NB*NF)
#define OFF_VAL (OFF_F0  + NB*NF)
#define OFF_JIT (OFF_VAL + NB*NF)
#define OFF_HNR (OFF_JIT + NB*4)
#define OFF_MAX (OFF_HNR + NB*NHNR_CHUNK*HNR_LAGS)   // NB uints
#define OFF_MSK (OFF_MAX + NB)                       // NB*2500 u64

__device__ __forceinline__ int imax_(int a, int b) { return a > b ? a : b; }

__device__ __forceinline__ uint pack_bf16(float a, float b) {
    uint ua = __builtin_bit_cast(uint, a), ub = __builtin_bit_cast(uint, b);
    ua = (ua + 0x8000u) >> 16; ub = (ub + 0x8000u) >> 16;
    return ua | (ub << 16);
}

__device__ __forceinline__ bf16x8 ld_b_frag(const uint* p) {
    union { uint u[4]; bf16x8 v; } t;
    t.u[0] = p[0]; t.u[1] = p[1]; t.u[2] = p[2]; t.u[3] = p[3];
    return t.v;
}

__device__ __forceinline__ float sgn_(float v) {
    return (float)(v > 0.f) - (float)(v < 0.f);
}

// ---------------------------------------------------------------------------
// K1: per-frame stats + autocorr peak via MFMA.  4 waves/block, 4 frames/wave.
// LDS-pipe-bound at CU level (R7 model: ~700 LDS-cyc/frame = 150us). Cuts:
//  (a) acc2 (lags 256..319) contributions are EXACTLY zero for j<8 (A2 reads
//      land wholly in the left zero-pad) -> run acc2 only j=8..12.
//  (b) A2(j) == A1(j-8) (256-elem shift) -> reuse A1 frags from a 5-deep
//      register history: A-reads 26->13 b128, MFMA 26->18 per frame.
//  (c) dual-copy B skew: xo at +370 dwords (==10 mod 32; was +480 == 0) so
//      even/odd lane pairs stop sharing banks -> kills the 6-way B conflicts.
// Per-wave LDS (dwords): xw [0,368), xo [370,738), region 744.
// Per copy (elems): [0,240) zero | [240,640) data | [640,736) zero.
// LESSONS (R5/R6): no per-frame global atomics; keep staging->MFMA barrier.
// ---------------------------------------------------------------------------
__global__ __launch_bounds__(256) void k_frame(const float* __restrict__ audio,
                                               float* __restrict__ ws)
{
    __shared__ __align__(16) uint lds[4][744];
    const int tid = threadIdx.x;
    const int widx = tid >> 6, lane = tid & 63;
    const int lo = lane & 15, q = lane >> 4;
    const int s = blockIdx.y;
    const int fbase = blockIdx.x * 16 + widx * 4;
    const float* as = audio + (size_t)s * NSAMP;

    uint* base = lds[widx];
    ull* zb = (ull*)base;
    const ushort* xw_us = (const ushort*)base;

    // zero pads once: ull idx [0,60) u [160,184) u [185,245) u [345,369)
    for (int i = lane; i < 168; i += 64) {
        int zi;
        if (i < 60)       zi = i;
        else if (i < 84)  zi = 160 + (i - 60);
        else if (i < 144) zi = 185 + (i - 84);
        else              zi = 345 + (i - 144);
        zb[zi] = 0ull;
    }

    // prefetch frame p=0
    float4 tA, tB; float bnA, bnB;
    {
        int f0 = fbase; if (f0 > NF - 1) f0 = NF - 1;
        const float* a = as + (size_t)f0 * HOP;
        tA  = ((const float4*)a)[lane];
        bnA = a[4 * lane + 4];
        tB.x = tB.y = tB.z = tB.w = 0.f; bnB = 0.f;
        if (lane < 36) {
            tB  = ((const float4*)a)[64 + lane];
            bnB = (lane < 35) ? a[4 * (64 + lane) + 4] : 0.f;
        }
    }

    for (int p = 0; p < 4; ++p) {
        int f = fbase + p; if (f > NF - 1) f = NF - 1;  // dup writes benign

        // ---- stats + pack current regs into LDS ----
        float ss, zc, amp;
        {
            ss  = tA.x*tA.x + tA.y*tA.y + tA.z*tA.z + tA.w*tA.w;
            amp = fmaxf(fmaxf(fabsf(tA.x), fabsf(tA.y)),
                        fmaxf(fabsf(tA.z), fabsf(tA.w)));
            zc  = fabsf(sgn_(tA.y) - sgn_(tA.x)) + fabsf(sgn_(tA.z) - sgn_(tA.y))
                + fabsf(sgn_(tA.w) - sgn_(tA.z)) + fabsf(sgn_(bnA) - sgn_(tA.w));
            ull w = (ull)pack_bf16(tA.x, tA.y) | ((ull)pack_bf16(tA.z, tA.w) << 32);
            ull o = (ull)pack_bf16(tA.y, tA.z) | ((ull)pack_bf16(tA.w, bnA) << 32);
            zb[60 + lane]  = w;    // xw data ull idx 60+vi (dword 120+2vi)
            zb[245 + lane] = o;    // xo data ull idx 245+vi (dword 490+2vi)
        }
        if (lane < 36) {  // batch B: vi = 64+lane
            ss += tB.x*tB.x + tB.y*tB.y + tB.z*tB.z + tB.w*tB.w;
            amp = fmaxf(amp, fmaxf(fmaxf(fabsf(tB.x), fabsf(tB.y)),
                                   fmaxf(fabsf(tB.z), fabsf(tB.w))));
            zc += fabsf(sgn_(tB.y) - sgn_(tB.x)) + fabsf(sgn_(tB.z) - sgn_(tB.y))
                + fabsf(sgn_(tB.w) - sgn_(tB.z));
            if (lane < 35) zc += fabsf(sgn_(bnB) - sgn_(tB.w));
            ull w = (ull)pack_bf16(tB.x, tB.y) | ((ull)pack_bf16(tB.z, tB.w) << 32);
            ull o = (ull)pack_bf16(tB.y, tB.z) | ((ull)pack_bf16(tB.w, bnB) << 32);
            zb[124 + lane] = w;
            zb[309 + lane] = o;
        }
        #pragma unroll
        for (int off = 32; off; off >>= 1) {
            ss += __shfl_xor(ss, off);
            zc += __shfl_xor(zc, off);
            amp = fmaxf(amp, __shfl_xor(amp, off));
        }

        __syncthreads();   // fence: staging drained; prefetch issued BELOW

        // ---- prefetch frame p+1 (lands during MFMA) ----
        float4 nA, nB; float nbA = 0.f, nbB = 0.f;
        nA.x = nA.y = nA.z = nA.w = 0.f; nB = nA;
        if (p < 3) {
            int fn = fbase + p + 1; if (fn > NF - 1) fn = NF - 1;
            const float* an = as + (size_t)fn * HOP;
            nA  = ((const float4*)an)[lane];
            nbA = an[4 * lane + 4];
            if (lane < 36) {
                nB  = ((const float4*)an)[64 + lane];
                nbB = (lane < 35) ? an[4 * (64 + lane) + 4] : 0.f;
            }
        }

        // ---- MFMA K-loop: 13 A-reads, 13 B-reads, 18 MFMA ----
        f32x4 acc1 = {0.f, 0.f, 0.f, 0.f};
        f32x4 acc2 = {0.f, 0.f, 0.f, 0.f};
        const int a_eb = 240 + 8 * q - 16 * lo;                 // elems, mult of 8
        const uint* bp = base + ((lo & 1) ? 370 : 0) + 120 + 4 * q + (lo >> 1);
        bf16x8 ah[5];

        #pragma unroll
        for (int j = 0; j < 13; ++j) {
            bf16x8 a1 = *(const bf16x8*)(xw_us + a_eb + 32 * j);
            bf16x8 b  = ld_b_frag(bp + 16 * j);
            acc1 = __builtin_amdgcn_mfma_f32_16x16x32_bf16(a1, b, acc1, 0, 0, 0);
            if (j < 5) ah[j] = a1;
            if (j >= 8)
                acc2 = __builtin_amdgcn_mfma_f32_16x16x32_bf16(ah[j - 8], b, acc2, 0, 0, 0);
        }

        float ac0 = __shfl(acc1[0], 0);

        float bv = -1e30f; int bl = 1 << 30;
        #pragma unroll
        for (int r = 0; r < 4; ++r) {
            int lag = 64 * q + 16 * r + lo;
            float v = acc1[r];
            if (lag >= 32 && v > bv) { bv = v; bl = lag; }
        }
        if (q == 0) {
            #pragma unroll
            for (int r = 0; r < 4; ++r) {
                int lag = 256 + 16 * r + lo;
                float v = acc2[r];
                if (v > bv) { bv = v; bl = lag; }
            }
        }
        #pragma unroll
        for (int off = 32; off; off >>= 1) {
            float ov = __shfl_xor(bv, off);
            int   ol = __shfl_xor(bl, off);
            if (ov > bv || (ov == bv && ol < bl)) { bv = ov; bl = ol; }
        }

        if (lane == 0) {
            float f0v = SR_F / (float)bl;
            int valid = (bv > 0.3f * ac0) && (f0v > 50.f) && (f0v < 500.f);
            size_t idx = (size_t)s * NF + f;
            ws[OFF_RMS + idx] = sqrtf(ss / (float)FRAME);
            ws[OFF_ZCR + idx] = zc / (2.f * (float)FRAME);
            ws[OFF_AMP + idx] = amp;
            ws[OFF_F0  + idx] = f0v;
            ws[OFF_VAL + idx] = valid ? 1.f : 0.f;
        }

        tA = nA; tB = nB; bnA = nbA; bnB = nbB;
        __syncthreads();   // protect next staging vs lagging readers
    }
}

// ---------------------------------------------------------------------------
// K2a: |a| max per sample.  20 blocks/sample, atomicMax on monotone uint bits.
// ---------------------------------------------------------------------------
__global__ __launch_bounds__(256) void k_absmax(const float* __restrict__ audio,
                                                float* __restrict__ ws)
{
    __shared__ float sred[4];
    const int s = blockIdx.y, b = blockIdx.x, tid = threadIdx.x;
    const float4* a = (const float4*)(audio + (size_t)s * NSAMP) + (size_t)b * 2000;
    float m = 0.f;
    for (int i = tid; i < 2000; i += 256) {
        float4 t = a[i];
        m = fmaxf(m, fmaxf(fmaxf(fabsf(t.x), fabsf(t.y)),
                           fmaxf(fabsf(t.z), fabsf(t.w))));
    }
    #pragma unroll
    for (int off = 32; off; off >>= 1) m = fmaxf(m, __shfl_xor(m, off));
    if ((tid & 63) == 0) sred[tid >> 6] = m;
    __syncthreads();
    if (tid == 0) {
        float mm = fmaxf(fmaxf(sred[0], sred[1]), fmaxf(sred[2], sred[3]));
        atomicMax((uint*)ws + OFF_MAX + s, __float_as_uint(mm));
    }
}

// ---------------------------------------------------------------------------
// K2b: crossing bitmask.  25 blocks/sample, ballot-packed to global.
// ---------------------------------------------------------------------------
__global__ __launch_bounds__(256) void k_cross(const float* __restrict__ audio,
                                               float* __restrict__ ws)
{
    const int s = blockIdx.y, b = blockIdx.x, tid = threadIdx.x;
    const float thr = 0.3f * __uint_as_float(((const uint*)ws)[OFF_MAX + s]);
    const float* a = audio + (size_t)s * NSAMP;
    unsigned long long* msk =
        (unsigned long long*)(ws + OFF_MSK) + (size_t)s * 2500 + (size_t)b * 100;
    const int base0 = b * 6400;
    #pragma unroll 5
    for (int it = 0; it < 25; ++it) {
        int i = base0 + it * 256 + tid;
        bool fl = (i < NSAMP - 1) && (a[i] < thr) && (a[i + 1] >= thr);
        unsigned long long bal = __ballot(fl);
        if ((tid & 63) == 0) msk[(it * 256 + tid) >> 6] = bal;
    }
}

// ---------------------------------------------------------------------------
// K2c: stitch — chunk states over the bitmask, associative merge.
// ---------------------------------------------------------------------------
__global__ __launch_bounds__(256) void k_jstitch(float* __restrict__ ws)
{
    __shared__ unsigned long long msk[2500];
    __shared__ int   s_cnt[256], s_p0[256], s_p1[256], s_pl[256], s_pl2[256];
    __shared__ float s_sum[256];
    const int s = blockIdx.x, tid = threadIdx.x;
    const unsigned long long* gm =
        (const unsigned long long*)(ws + OFF_MSK) + (size_t)s * 2500;
    for (int i = tid; i < 2500; i += 256) msk[i] = gm[i];
    __syncthreads();

    if (tid < 250) {
        int cnt = 0, p0 = 0, p1 = 0, pl = 0, pl2 = 0;
        float sum = 0.f;
        for (int wi = 0; wi < 10; ++wi) {
            unsigned long long word = msk[tid * 10 + wi];
            int wb = (tid * 10 + wi) << 6;
            while (word) {
                int b = __builtin_ctzll(word);
                word &= word - 1;
                int pos = wb + b + 1;
                if (cnt >= 2) sum += fabsf((float)((pos - pl) - (pl - pl2)));
                if (cnt == 0) p0 = pos;
                if (cnt == 1) p1 = pos;
                pl2 = pl; pl = pos; ++cnt;
            }
        }
        s_cnt[tid] = cnt; s_p0[tid] = p0; s_p1[tid] = p1;
        s_pl[tid] = pl; s_pl2[tid] = pl2; s_sum[tid] = sum;
    }
    __syncthreads();

    if (tid == 0) {
        int Ac = 0, Ap0 = 0, Ap1 = 0, Apl = 0, Apl2 = 0; float As = 0.f;
        for (int c = 0; c < 250; ++c) {
            int rc = s_cnt[c]; if (!rc) continue;
            int rp0 = s_p0[c], rp1 = s_p1[c], rpl = s_pl[c], rpl2 = s_pl2[c];
            float rs = s_sum[c];
            if (Ac == 0) { Ac = rc; Ap0 = rp0; Ap1 = rp1; Apl = rpl; Apl2 = rpl2; As = rs; continue; }
            int pb = rp0 - Apl;
            As += rs;
            if (Ac >= 2) As += fabsf((float)(pb - (Apl - Apl2)));
            if (rc >= 2) As += fabsf((float)((rp1 - rp0) - pb));
            if (Ac == 1) Ap1 = rp0;
            Apl2 = (rc >= 2) ? rpl2 : Apl;
            Apl = rpl;
            Ac += rc;
        }
        float* j = ws + OFF_JIT + s * 4;
        j[0] = (float)Ac; j[1] = (float)Ap0; j[2] = (float)Apl; j[3] = As;
    }
}

// ---------------------------------------------------------------------------
// K3: HNR partial autocorr via MFMA, lags 50..199 (as 48+16m+n).  R4 layout.
// ---------------------------------------------------------------------------
__global__ __launch_bounds__(256) void k_hnr(const float* __restrict__ audio,
                                             float* __restrict__ ws)
{
    __shared__ __align__(16) ushort hx[4][2][HWIN];
    const int tid = threadIdx.x;
    const int widx = tid >> 6, lane = tid & 63;
    const int lo = lane & 15, q = lane >> 4;
    const int s = blockIdx.y;
    const int c = blockIdx.x * 4 + widx;
    const float* a = audio + (size_t)s * NSAMP;

    ushort* xw = &hx[widx][0][0];
    ushort* xo = &hx[widx][1][0];
    uint* xwd = (uint*)xw;
    uint* xod = (uint*)xo;

    const int aoff = 240 + 8 * q - 16 * lo;
    const uint* bw = (lo & 1) ? xod : xwd;
    const int boff = 144 + 4 * q + (lo >> 1);

    f32x4 acc = {0.f, 0.f, 0.f, 0.f};

    for (int tile = 0; tile < JCH / TJ; ++tile) {
        const int g0 = 32 * (c * JCH + tile * TJ) - 288;
        __syncthreads();
        for (int v = lane; v < HWIN / 4; v += 64) {
            int g = g0 + 4 * v;
            float x0, x1, x2, x3, x4;
            if (g >= 0 && g + 4 < NSAMP) {
                float4 t = *(const float4*)(a + g);
                x0 = t.x; x1 = t.y; x2 = t.z; x3 = t.w;
                x4 = a[g + 4];
            } else {
                x0 = (g     >= 0 && g     < NSAMP) ? a[g]     : 0.f;
                x1 = (g + 1 >= 0 && g + 1 < NSAMP) ? a[g + 1] : 0.f;
                x2 = (g + 2 >= 0 && g + 2 < NSAMP) ? a[g + 2] : 0.f;
                x3 = (g + 3 >= 0 && g + 3 < NSAMP) ? a[g + 3] : 0.f;
                x4 = (g + 4 >= 0 && g + 4 < NSAMP) ? a[g + 4] : 0.f;
            }
            int d = 2 * v;
            xwd[d] = pack_bf16(x0, x1); xwd[d + 1] = pack_bf16(x2, x3);
            xod[d] = pack_bf16(x1, x2); xod[d + 1] = pack_bf16(x3, x4);
        }
        __syncthreads();

        #pragma unroll
        for (int jl = 0; jl < TJ; ++jl) {
            bf16x8 af = *(const bf16x8*)(xw + aoff + 32 * jl);
            bf16x8 bf = ld_b_frag(bw + boff + 16 * jl);
            acc = __builtin_amdgcn_mfma_f32_16x16x32_bf16(af, bf, acc, 0, 0, 0);
        }
    }

    #pragma unroll
    for (int r = 0; r < 4; ++r) {
        int row = 4 * q + r;
        int lag = 48 + 16 * row + lo;
        if (row < 10 && lag >= 50 && lag < 200)
            ws[OFF_HNR + ((size_t)s * NHNR_CHUNK + c) * HNR_LAGS + (lag - 50)] = acc[r];
    }
}

// ---------------------------------------------------------------------------
// K4: per-sample finalize + MLP
// ---------------------------------------------------------------------------
__global__ __launch_bounds__(256) void k_final(const float* __restrict__ ws,
        const float* __restrict__ W1, const float* __restrict__ b1,
        const float* __restrict__ gam, const float* __restrict__ bet,
        const float* __restrict__ W2, const float* __restrict__ b2,
        float* __restrict__ out)
{
    __shared__ float samp[NF];
    __shared__ float sac[HNR_LAGS];
    __shared__ float sred[32];
    __shared__ float sstat[12];
    __shared__ float sfeats[10];
    __shared__ float shid[64];

    const int s = blockIdx.x;
    const int tid = threadIdx.x;
    const float* rmsA = ws + OFF_RMS + (size_t)s * NF;
    const float* zcrA = ws + OFF_ZCR + (size_t)s * NF;
    const float* ampA = ws + OFF_AMP + (size_t)s * NF;
    const float* f0A  = ws + OFF_F0  + (size_t)s * NF;
    const float* valA = ws + OFF_VAL + (size_t)s * NF;

    float a0=0,a1=0,a2=0,a3=0,a4=0,a5=0,a6=0,a7=0;
    for (int i = tid; i < NF; i += 256) {
        float r = rmsA[i], z = zcrA[i], f0 = f0A[i], v = valA[i];
        samp[i] = ampA[i];
        a0 += r; a1 += r * r; a2 += z; a3 += z * z;
        a4 += f0 * v; a5 += f0 * f0 * v; a6 += v;
        a7 += (r > 0.01f && z < 0.3f) ? 1.f : 0.f;
    }
    #pragma unroll
    for (int off = 32; off; off >>= 1) {
        a0 += __shfl_xor(a0, off); a1 += __shfl_xor(a1, off);
        a2 += __shfl_xor(a2, off); a3 += __shfl_xor(a3, off);
        a4 += __shfl_xor(a4, off); a5 += __shfl_xor(a5, off);
        a6 += __shfl_xor(a6, off); a7 += __shfl_xor(a7, off);
    }
    if ((tid & 63) == 0) {
        int w = tid >> 6;
        sred[w*8+0]=a0; sred[w*8+1]=a1; sred[w*8+2]=a2; sred[w*8+3]=a3;
        sred[w*8+4]=a4; sred[w*8+5]=a5; sred[w*8+6]=a6; sred[w*8+7]=a7;
    }
    __syncthreads();

    if (tid < HNR_LAGS) {
        float acc = 0.f;
        const float* p = ws + OFF_HNR + (size_t)s * NHNR_CHUNK * HNR_LAGS + tid;
        for (int c = 0; c < NHNR_CHUNK; ++c) acc += p[c * HNR_LAGS];
        sac[tid] = acc;
    }
    if (tid == 0) {
        for (int k = 0; k < 8; ++k)
            sstat[k] = sred[k] + sred[8+k] + sred[16+k] + sred[24+k];
    }
    __syncthreads();

    if (tid < HNR_LAGS) {
        float v = sac[tid];
        int r = 0;
        for (int j = 0; j < HNR_LAGS; ++j) {
            float vj = sac[j];
            r += (vj < v) || (vj == v && j < tid);
        }
        if (r == 14) sstat[8] = v;
        if (r == 15) sstat[9] = v;
    }
    if (tid == 192) {
        float mx = sac[0];
        for (int j = 1; j < HNR_LAGS; ++j) mx = fmaxf(mx, sac[j]);
        sstat[10] = mx;
    }
    if (tid == 224) {
        int ka = 0; float sum_amp = 0.f, sum_ad = 0.f, prev = 0.f;
        for (int i = 0; i < NF; ++i) {
            float amp = samp[i];
            if (amp > 0.01f) {
                if (ka >= 1) sum_ad += fabsf(amp - prev);
                sum_amp += amp; prev = amp; ++ka;
            }
        }
        float mean_amp = sum_amp / (float)imax_(ka, 1);
        float mean_ad  = sum_ad  / (float)imax_(ka - 1, 1);
        sstat[11] = (ka >= 2 && mean_amp > 0.f)
            ? fminf(fmaxf(mean_ad / fmaxf(mean_amp, 1e-12f), 0.f), 1.f) : 0.f;
    }
    __syncthreads();

    if (tid == 0) {
        float S_r = sstat[0], S_r2 = sstat[1], S_z = sstat[2], S_z2 = sstat[3];
        float S_f = sstat[4], S_f2 = sstat[5], S_v = sstat[6], S_voi = sstat[7];
        float e_mean = S_r / (float)NF;
        float e_std  = sqrtf(fmaxf(S_r2 / (float)NF - e_mean * e_mean, 0.f));
        float z_mean = S_z / (float)NF;
        float z_std  = sqrtf(fmaxf(S_z2 / (float)NF - z_mean * z_mean, 0.f));
        float f0_mean = 0.f, f0_std = 0.f;
        if (S_v > 0.f) {
            f0_mean = S_f / S_v;
            f0_std  = sqrtf(fmaxf(S_f2 / S_v - f0_mean * f0_mean, 0.f));
        }
        const float* jp = ws + OFF_JIT + s * 4;
        int k = (int)jp[0];
        float pp0 = jp[1], ppl = jp[2], psum = jp[3];
        int nper = k - 1;
        float mean_period = (k >= 2) ? (ppl - pp0) / (float)(k - 1) : 0.f;
        float mean_pd = psum / (float)imax_(nper - 1, 1);
        float jit = (nper >= 2 && mean_period > 0.f)
            ? fminf(fmaxf(mean_pd / fmaxf(mean_period, 1e-12f), 0.f), 1.f) : 0.f;
        if (f0_mean < 50.f || f0_mean > 500.f) jit = 0.f;
        float noise = 0.1f * sstat[8] + 0.9f * sstat[9];
        float hnr = (noise > 0.f)
            ? fminf(fmaxf(sstat[10] / fmaxf(noise, 1e-30f) / 100.f, 0.f), 1.f) : 0.f;
        float shim = sstat[11];
        float voice = S_voi / (float)NF;

        float mt[10] = {f0_mean, f0_std, e_mean, e_std, z_mean, z_std, jit, shim, hnr, voice};
        for (int i = 0; i < 10; ++i) out[NB * 128 + s * 10 + i] = mt[i];
        sfeats[0] = f0_mean / 500.f;
        sfeats[1] = f0_std / 100.f;
        for (int i = 2; i < 10; ++i) sfeats[i] = mt[i];
    }
    __syncthreads();

    if (tid < 64) {
        float h = b1[tid];
        #pragma unroll
        for (int i = 0; i < 10; ++i) h = fmaf(sfeats[i], W1[tid * 10 + i], h);
        float sum = h, sq = h * h;
        #pragma unroll
        for (int off = 32; off; off >>= 1) {
            sum += __shfl_xor(sum, off);
            sq  += __shfl_xor(sq, off);
        }
        float mu = sum / 64.f;
        float var = sq / 64.f - mu * mu;
        float hn = (h - mu) * rsqrtf(var + 1e-5f) * gam[tid] + bet[tid];
        shid[tid] = fmaxf(hn, 0.f);
    }
    __syncthreads();
    if (tid < 128) {
        float accv = b2[tid];
        #pragma unroll 8
        for (int j = 0; j < 64; ++j) accv = fmaf(shid[j], W2[tid * 64 + j], accv);
        out[(size_t)s * 128 + tid] = accv;
    }
}

// ---------------------------------------------------------------------------
extern "C" void kernel_launch(void* const* d_in, const int* in_sizes, int n_in,
                              void* d_out, int out_size, void* d_ws, size_t ws_size,
                              hipStream_t stream)
{
    const float* audio = (const float*)d_in[0];
    const float* W1    = (const float*)d_in[1];
    const float* b1    = (const float*)d_in[2];
    const float* gam   = (const float*)d_in[3];
    const float* bet   = (const float*)d_in[4];
    const float* W2    = (const float*)d_in[5];
    const float* b2    = (const float*)d_in[6];
    float* out = (float*)d_out;
    float* ws  = (float*)d_ws;

    hipMemsetAsync((uint*)ws + OFF_MAX, 0, NB * sizeof(uint), stream);
    hipLaunchKernelGGL(k_frame,   dim3((NF + 15) / 16, NB), dim3(256), 0, stream, audio, ws);
    hipLaunchKernelGGL(k_absmax,  dim3(20, NB),             dim3(256), 0, stream, audio, ws);
    hipLaunchKernelGGL(k_cross,   dim3(25, NB),             dim3(256), 0, stream, audio, ws);
    hipLaunchKernelGGL(k_jstitch, dim3(NB),                 dim3(256), 0, stream, ws);
    hipLaunchKernelGGL(k_hnr,     dim3(NHNR_CHUNK / 4, NB), dim3(256), 0, stream, audio, ws);
    hipLaunchKernelGGL(k_final,   dim3(NB),                 dim3(256), 0, stream,
                       ws, W1, b1, gam, bet, W2, b2, out);
}